// Round 7
// baseline (866.273 us; speedup 1.0000x reference)
//
#include <hip/hip_runtime.h>

#define H 256

typedef __attribute__((ext_vector_type(8))) short bf16x8;
typedef __attribute__((ext_vector_type(4))) float f32x4;

__device__ __forceinline__ float b2f(ushort h) {
    return __uint_as_float(((unsigned)h) << 16);
}
__device__ __forceinline__ float b2f_lo(unsigned u) {  // low bf16 of packed pair
    return __uint_as_float(u << 16);
}
__device__ __forceinline__ float b2f_hi(unsigned u) {  // high bf16 of packed pair
    return __uint_as_float(u & 0xffff0000u);
}
__device__ __forceinline__ ushort f2bf(float f) {
    unsigned u = __float_as_uint(f);
    unsigned r = (u + 0x7FFF + ((u >> 16) & 1)) >> 16;  // RNE
    return (ushort)r;
}
__device__ __forceinline__ unsigned pack2bf(float lo, float hi) {
    return (unsigned)f2bf(lo) | ((unsigned)f2bf(hi) << 16);
}

// async global->LDS DMA, 16B per lane, wave-uniform LDS base + lane*16 (HW-defined)
__device__ __forceinline__ void gload16(const ushort* g, const short* l) {
    __builtin_amdgcn_global_load_lds(
        (const __attribute__((address_space(1))) void*)(const void*)g,
        (__attribute__((address_space(3))) void*)(void*)l, 16, 0, 0);
}

// ---------------- CSR build ----------------
__global__ __launch_bounds__(256) void k_zero2_i(int* p, int* q, int n) {
    int i = blockIdx.x * 256 + threadIdx.x;
    if (i < n) { p[i] = 0; q[i] = 0; }
}

__global__ __launch_bounds__(256) void k_zero_f(float* p, int n) {
    int i = blockIdx.x * 256 + threadIdx.x;
    if (i < n) p[i] = 0.f;
}

__global__ __launch_bounds__(256) void k_count_deg_i(const int* __restrict__ dst, int* cnt, int E) {
    int i = blockIdx.x * 256 + threadIdx.x;
    if (i < E) atomicAdd(&cnt[dst[i]], 1);
}

__global__ __launch_bounds__(256) void k_scan1(const int* __restrict__ cnt, int* __restrict__ partial,
                                               int* __restrict__ bsums, int N) {
    __shared__ int s[256];
    int t = threadIdx.x;
    int idx = blockIdx.x * 256 + t;
    int v = idx < N ? cnt[idx] : 0;
    s[t] = v;
    __syncthreads();
    for (int off = 1; off < 256; off <<= 1) {
        int add = (t >= off) ? s[t - off] : 0;
        __syncthreads();
        s[t] += add;
        __syncthreads();
    }
    if (idx < N) partial[idx] = s[t];
    if (t == 255) bsums[blockIdx.x] = s[t];
}

__global__ __launch_bounds__(1024) void k_scan2(int* bsums, int nb) {
    __shared__ int s[1024];
    int t = threadIdx.x;
    s[t] = (t < nb) ? bsums[t] : 0;
    __syncthreads();
    for (int off = 1; off < 1024; off <<= 1) {
        int add = (t >= off) ? s[t - off] : 0;
        __syncthreads();
        s[t] += add;
        __syncthreads();
    }
    if (t < nb) bsums[t] = s[t];
}

// rowptr + dinv/selfw in one pass
__global__ __launch_bounds__(256) void k_scan3(const int* __restrict__ partial, const int* __restrict__ bsums,
                                               const int* __restrict__ cnt,
                                               int* __restrict__ rowptr, float* __restrict__ dinv,
                                               float* __restrict__ selfw, int N) {
    int idx = blockIdx.x * 256 + threadIdx.x;
    if (idx < N) {
        int off = blockIdx.x > 0 ? bsums[blockIdx.x - 1] : 0;
        rowptr[idx + 1] = partial[idx] + off;
        if (idx == 0) rowptr[0] = 0;
        float d = 1.0f + (float)cnt[idx];
        dinv[idx] = rsqrtf(d);
        selfw[idx] = 1.0f / d;
    }
}

__global__ __launch_bounds__(256) void k_scatter(const int* __restrict__ src, const int* __restrict__ dst,
                                                 const float* __restrict__ dinv, const int* __restrict__ rowptr,
                                                 int* __restrict__ fill, int* __restrict__ esrc,
                                                 float* __restrict__ ewt, int E) {
    int e = blockIdx.x * 256 + threadIdx.x;
    if (e >= E) return;
    int s = src[e], d = dst[e];
    int pos = rowptr[d] + atomicAdd(&fill[d], 1);
    esrc[pos] = s;
    ewt[pos] = dinv[s] * dinv[d];
}

// ---------------- batched conversions: x->bf16 + all 8 weight transposes ----------------
__device__ __forceinline__ void tcvt_one(long i, const float* __restrict__ W, ushort* __restrict__ Wt,
                                         int K, int M) {
    int k = (int)(i / M), m = (int)(i - (long)k * M);
    Wt[(size_t)m * K + k] = f2bf(W[(size_t)k * M + m]);
}

__global__ __launch_bounds__(256) void k_prep(
    const float* __restrict__ x, ushort* __restrict__ xh, long nx, int DIN,
    const float* __restrict__ Wc1, ushort* Wc1t, const float* __restrict__ Wd1, ushort* Wd1t,
    const float* __restrict__ Wc2, ushort* Wc2t, const float* __restrict__ Wd2, ushort* Wd2t,
    const float* __restrict__ Wc3, ushort* Wc3t, const float* __restrict__ Wd3, ushort* Wd3t,
    const float* __restrict__ Wp1, ushort* Wp1t, const float* __restrict__ Wp2, ushort* Wp2t) {
    long i = (long)blockIdx.x * 256 + threadIdx.x;
    if (i < nx) { xh[i] = f2bf(x[i]); return; }
    i -= nx;
    long n1 = (long)DIN * 256;
    if (i < n1) { tcvt_one(i, Wc1, Wc1t, DIN, 256); return; }
    i -= n1;
    if (i < n1) { tcvt_one(i, Wd1, Wd1t, DIN, 256); return; }
    i -= n1;
    if (i < 65536) { tcvt_one(i, Wc2, Wc2t, 256, 256); return; }
    i -= 65536;
    if (i < 65536) { tcvt_one(i, Wd2, Wd2t, 256, 256); return; }
    i -= 65536;
    if (i < 65536) { tcvt_one(i, Wc3, Wc3t, 256, 256); return; }
    i -= 65536;
    if (i < 65536) { tcvt_one(i, Wd3, Wd3t, 256, 256); return; }
    i -= 32768 * 2;
    if (i < 32768) { tcvt_one(i, Wp1, Wp1t, 256, 128); return; }
    i -= 32768;
    if (i < 32768) { tcvt_one(i, Wp2, Wp2t, 128, 256); return; }
}

// ---------------- CSR gather (bf16 in, fp32 acc, bf16 out) ----------------
// b4: 1 node per wave, ushort4/lane (proven fastest variant, round-2: 83.0us).
// Round-3 A/B showed the gather is service-rate-bound (random 512B granules), not
// latency/issue-bound: doubling bytes/instr and in-flight bytes changed nothing.
__global__ __launch_bounds__(256) void k_gather_b4(const ushort* __restrict__ xin, const int* __restrict__ rowptr,
                                                   const int* __restrict__ esrc, const float* __restrict__ ewt,
                                                   const float* __restrict__ selfw, ushort* __restrict__ p,
                                                   int N, int SX, int SP) {
    int node = blockIdx.x * 4 + (threadIdx.x >> 6);
    if (node >= N) return;
    int c = (threadIdx.x & 63) << 2;
    ushort4 h = *(const ushort4*)(xin + (size_t)node * SX + c);
    float sw = selfw[node];
    float a0 = b2f(h.x) * sw, a1 = b2f(h.y) * sw, a2 = b2f(h.z) * sw, a3 = b2f(h.w) * sw;
    int j = rowptr[node], r1 = rowptr[node + 1];
    for (; j + 3 < r1; j += 4) {
        int s0 = esrc[j], s1 = esrc[j + 1], s2 = esrc[j + 2], s3 = esrc[j + 3];
        float w0 = ewt[j], w1 = ewt[j + 1], w2 = ewt[j + 2], w3 = ewt[j + 3];
        ushort4 v0 = *(const ushort4*)(xin + (size_t)s0 * SX + c);
        ushort4 v1 = *(const ushort4*)(xin + (size_t)s1 * SX + c);
        ushort4 v2 = *(const ushort4*)(xin + (size_t)s2 * SX + c);
        ushort4 v3 = *(const ushort4*)(xin + (size_t)s3 * SX + c);
        a0 += b2f(v0.x) * w0 + b2f(v1.x) * w1 + b2f(v2.x) * w2 + b2f(v3.x) * w3;
        a1 += b2f(v0.y) * w0 + b2f(v1.y) * w1 + b2f(v2.y) * w2 + b2f(v3.y) * w3;
        a2 += b2f(v0.z) * w0 + b2f(v1.z) * w1 + b2f(v2.z) * w2 + b2f(v3.z) * w3;
        a3 += b2f(v0.w) * w0 + b2f(v1.w) * w1 + b2f(v2.w) * w2 + b2f(v3.w) * w3;
    }
    for (; j < r1; ++j) {
        int s0 = esrc[j];
        float w0 = ewt[j];
        ushort4 v0 = *(const ushort4*)(xin + (size_t)s0 * SX + c);
        a0 += b2f(v0.x) * w0; a1 += b2f(v0.y) * w0; a2 += b2f(v0.z) * w0; a3 += b2f(v0.w) * w0;
    }
    ushort4 o;
    o.x = f2bf(a0); o.y = f2bf(a1); o.z = f2bf(a2); o.w = f2bf(a3);
    *(ushort4*)(p + (size_t)node * SP + c) = o;
}

// 4 nodes per wave (16-lane group per node), 16B per lane covers a 256B (128-col) row.
__global__ __launch_bounds__(256) void k_gather_b2(const ushort* __restrict__ xin, const int* __restrict__ rowptr,
                                                   const int* __restrict__ esrc, const float* __restrict__ ewt,
                                                   const float* __restrict__ selfw, ushort* __restrict__ p,
                                                   int N, int SX, int SP) {
    int node = blockIdx.x * 16 + (threadIdx.x >> 4);
    bool act = node < N;
    int nn = act ? node : N - 1;
    int c = (threadIdx.x & 15) << 3;  // 8 cols (16B) per lane, 16 lanes = 128 cols
    uint4 hv = *(const uint4*)(xin + (size_t)nn * SX + c);
    float sw = selfw[nn];
    float a0 = b2f_lo(hv.x) * sw, a1 = b2f_hi(hv.x) * sw;
    float a2 = b2f_lo(hv.y) * sw, a3 = b2f_hi(hv.y) * sw;
    float a4 = b2f_lo(hv.z) * sw, a5 = b2f_hi(hv.z) * sw;
    float a6 = b2f_lo(hv.w) * sw, a7 = b2f_hi(hv.w) * sw;
    int j = act ? rowptr[nn] : 0, r1 = act ? rowptr[nn + 1] : 0;
    for (; j + 3 < r1; j += 4) {
        int s0 = esrc[j], s1 = esrc[j + 1], s2 = esrc[j + 2], s3 = esrc[j + 3];
        float w0 = ewt[j], w1 = ewt[j + 1], w2 = ewt[j + 2], w3 = ewt[j + 3];
        uint4 v0 = *(const uint4*)(xin + (size_t)s0 * SX + c);
        uint4 v1 = *(const uint4*)(xin + (size_t)s1 * SX + c);
        uint4 v2 = *(const uint4*)(xin + (size_t)s2 * SX + c);
        uint4 v3 = *(const uint4*)(xin + (size_t)s3 * SX + c);
        a0 += b2f_lo(v0.x) * w0 + b2f_lo(v1.x) * w1 + b2f_lo(v2.x) * w2 + b2f_lo(v3.x) * w3;
        a1 += b2f_hi(v0.x) * w0 + b2f_hi(v1.x) * w1 + b2f_hi(v2.x) * w2 + b2f_hi(v3.x) * w3;
        a2 += b2f_lo(v0.y) * w0 + b2f_lo(v1.y) * w1 + b2f_lo(v2.y) * w2 + b2f_lo(v3.y) * w3;
        a3 += b2f_hi(v0.y) * w0 + b2f_hi(v1.y) * w1 + b2f_hi(v2.y) * w2 + b2f_hi(v3.y) * w3;
        a4 += b2f_lo(v0.z) * w0 + b2f_lo(v1.z) * w1 + b2f_lo(v2.z) * w2 + b2f_lo(v3.z) * w3;
        a5 += b2f_hi(v0.z) * w0 + b2f_hi(v1.z) * w1 + b2f_hi(v2.z) * w2 + b2f_hi(v3.z) * w3;
        a6 += b2f_lo(v0.w) * w0 + b2f_lo(v1.w) * w1 + b2f_lo(v2.w) * w2 + b2f_lo(v3.w) * w3;
        a7 += b2f_hi(v0.w) * w0 + b2f_hi(v1.w) * w1 + b2f_hi(v2.w) * w2 + b2f_hi(v3.w) * w3;
    }
    for (; j < r1; ++j) {
        int s0 = esrc[j];
        float w0 = ewt[j];
        uint4 v0 = *(const uint4*)(xin + (size_t)s0 * SX + c);
        a0 += b2f_lo(v0.x) * w0; a1 += b2f_hi(v0.x) * w0;
        a2 += b2f_lo(v0.y) * w0; a3 += b2f_hi(v0.y) * w0;
        a4 += b2f_lo(v0.z) * w0; a5 += b2f_hi(v0.z) * w0;
        a6 += b2f_lo(v0.w) * w0; a7 += b2f_hi(v0.w) * w0;
    }
    if (act) {
        uint4 o;
        o.x = pack2bf(a0, a1); o.y = pack2bf(a2, a3);
        o.z = pack2bf(a4, a5); o.w = pack2bf(a6, a7);
        *(uint4*)(p + (size_t)node * SP + c) = o;
    }
}

// ---------------- fused dual-GEMM MFMA v4:  Out = relu(Pm@Wc + bc) + X@Wd + bd ----------------
// 64 rows x 256 cols per block, 4 waves, wave = 64-col slab, dual 4x4 acc.
// v4 changes vs v3 (T3-minimum 2-phase, plain HIP):
//  * inputs (Ps/Xs) double-buffered: next K-step's gload16 DMAs are issued BEFORE computing the
//    current step, so the single per-step __syncthreads drain finds them already landed.
//  * weights are NOT staged in LDS: each lane's B-fragment is 16 contiguous bytes at
//    Wt[col*K + k0 + slot*8] -- loaded directly from global (L2-hot, wave-private, no barrier).
//  * 1 barrier per K-step instead of 2; LDS 80KB -> 32KB.
// Input staging/swizzle identical to v3 (proven SQ_LDS_BANK_CONFLICT == 0).
// dopool: layer-3 epilogue accumulates the batch mean-pool numerator (ge); sbatch reuses Ps.
__global__ __launch_bounds__(256, 2) void k_fused_mfma(
    const ushort* __restrict__ Pm, const ushort* __restrict__ X,
    const ushort* __restrict__ Wct, const ushort* __restrict__ Wdt,
    const float* __restrict__ bc, const float* __restrict__ bd,
    ushort* __restrict__ Out, int N, int K, int SP, int SX,
    const int* __restrict__ batch, float* __restrict__ gesum, int dopool) {
    __shared__ __align__(16) short Ps[2][64 * 64];
    __shared__ __align__(16) short Xs[2][64 * 64];
    const int tid = threadIdx.x;
    const int wave = tid >> 6, lane = tid & 63;
    const int row0 = blockIdx.x * 64;

    f32x4 accC[4][4], accD[4][4];
#pragma unroll
    for (int i = 0; i < 4; ++i)
#pragma unroll
        for (int j = 0; j < 4; ++j) { accC[i][j] = (f32x4)0.f; accD[i][j] = (f32x4)0.f; }

    const int lr = lane >> 3;          // staging: row within 8-row slab
    const int ls = lane & 7;           // staging: physical 16B slot within 128B row
    const int swz = (ls ^ lr) << 3;    // pre-swizzled source offset (halves)
    const int m = lane & 15, t4 = lane >> 4;

    // clamped global rows for this wave's two staging slabs
    int gr0 = row0 + wave * 16 + lr;      if (gr0 > N - 1) gr0 = N - 1;
    int gr1 = row0 + wave * 16 + 8 + lr;  if (gr1 > N - 1) gr1 = N - 1;
    const int rr0 = wave * 16, rr1 = wave * 16 + 8;

    // prologue: stage k=0 into buffer 0
    gload16(Pm + (size_t)gr0 * SP + swz, &Ps[0][rr0 * 64]);
    gload16(X + (size_t)gr0 * SX + swz, &Xs[0][rr0 * 64]);
    gload16(Pm + (size_t)gr1 * SP + swz, &Ps[0][rr1 * 64]);
    gload16(X + (size_t)gr1 * SX + swz, &Xs[0][rr1 * 64]);
    __syncthreads();

    const int S = K >> 6;
    int cur = 0;
    for (int s = 0; s < S; ++s) {
        const int k0 = s << 6;
        // prefetch next K-step's inputs into the other buffer BEFORE computing:
        // the DMA latency hides under this step's loads + MFMA.
        if (s + 1 < S) {
            const int kn = k0 + 64;
            gload16(Pm + (size_t)gr0 * SP + kn + swz, &Ps[cur ^ 1][rr0 * 64]);
            gload16(X + (size_t)gr0 * SX + kn + swz, &Xs[cur ^ 1][rr0 * 64]);
            gload16(Pm + (size_t)gr1 * SP + kn + swz, &Ps[cur ^ 1][rr1 * 64]);
            gload16(X + (size_t)gr1 * SX + kn + swz, &Xs[cur ^ 1][rr1 * 64]);
        }
#pragma unroll
        for (int h = 0; h < 2; ++h) {
            const int slot = h * 4 + t4;
            bf16x8 aP[4], aX[4], bC[4], bD[4];
#pragma unroll
            for (int i = 0; i < 4; ++i) {
                int r = 16 * i + m;
                int off = r * 64 + ((slot ^ (r & 7)) << 3);
                aP[i] = *(bf16x8*)&Ps[cur][off];
                aX[i] = *(bf16x8*)&Xs[cur][off];
            }
            // weight fragments straight from global: 16B per lane, wave-private (no barrier).
#pragma unroll
            for (int j = 0; j < 4; ++j) {
                int c = wave * 64 + 16 * j + m;
                size_t goff = (size_t)c * K + k0 + slot * 8;
                bC[j] = *(const bf16x8*)(Wct + goff);
                bD[j] = *(const bf16x8*)(Wdt + goff);
            }
#pragma unroll
            for (int i = 0; i < 4; ++i)
#pragma unroll
                for (int j = 0; j < 4; ++j) {
                    accC[i][j] = __builtin_amdgcn_mfma_f32_16x16x32_bf16(aP[i], bC[j], accC[i][j], 0, 0, 0);
                    accD[i][j] = __builtin_amdgcn_mfma_f32_16x16x32_bf16(aX[i], bD[j], accD[i][j], 0, 0, 0);
                }
        }
        __syncthreads();  // drains the prefetch DMA (already landed) + protects buffers
        cur ^= 1;
    }

    // after the final barrier every wave is done with LDS -> Ps region reusable
    int* sb = (int*)&Ps[0][0];
    if (dopool && tid < 64) {
        int r = row0 + tid;
        sb[tid] = batch[r < N ? r : (N - 1)];
    }

    const int rq = t4 * 4;
#pragma unroll
    for (int j = 0; j < 4; ++j) {
        int col = wave * 64 + 16 * j + m;
        float bcv = bc[col], bdv = bd[col];
#pragma unroll
        for (int i = 0; i < 4; ++i)
#pragma unroll
            for (int g = 0; g < 4; ++g) {
                int row = row0 + 16 * i + rq + g;
                if (row < N) {
                    float v = fmaxf(accC[i][j][g] + bcv, 0.f) + accD[i][j][g] + bdv;
                    Out[(size_t)row * 256 + col] = f2bf(v);
                }
            }
    }

    if (dopool) {
        __syncthreads();
        const int g0 = sb[0], g1 = sb[63];
        for (int g = g0; g <= g1; ++g) {
#pragma unroll
            for (int j = 0; j < 4; ++j) {
                int col = wave * 64 + 16 * j + m;
                float bcv = bc[col], bdv = bd[col];
                float s = 0.f;
#pragma unroll
                for (int i = 0; i < 4; ++i)
#pragma unroll
                    for (int q = 0; q < 4; ++q) {
                        int rl = 16 * i + rq + q;
                        bool ok = (sb[rl] == g) && (row0 + rl < N);
                        float v = fmaxf(accC[i][j][q] + bcv, 0.f) + accD[i][j][q] + bdv;
                        s += ok ? v : 0.f;
                    }
                s += __shfl_down(s, 32, 64);
                s += __shfl_down(s, 16, 64);
                if (lane < 16) atomicAdd(&gesum[(size_t)g * 256 + wave * 64 + 16 * j + lane], s);
            }
        }
    }
}

// ---------------- fused pattern chain v2: pe += pool(relu(relu(Bb@Wp1+bp1)@Wp2+bp2)) ----------
// GEMM2 runs in two 128-col halves through ONE 32KB Wp2 staging buffer. Half-0's staging is
// issued at kernel entry (drained for free by GEMM1's first barrier); only half-1's 32KB stage is
// exposed, overlapped by the co-resident block. LDS = 32+16+8+16KB + sbatch ~= 72.3KB -> 2 blocks/CU.
__global__ __launch_bounds__(256, 2) void k_pat_fused(
    const ushort* __restrict__ Bb, const ushort* __restrict__ Wp1t, const ushort* __restrict__ Wp2t,
    const float* __restrict__ bp1, const float* __restrict__ bp2,
    const int* __restrict__ batch, float* __restrict__ pesum, int N) {
    __shared__ __align__(16) short Wp2s[128 * 128];  // 32KB: one 128-col half of Wp2 at a time
    __shared__ __align__(16) short Wp1s[128 * 64];   // 16KB
    __shared__ __align__(16) short Bbs[64 * 64];     // 8KB
    __shared__ __align__(16) short Ts[64 * 128];     // 16KB
    __shared__ int sbatch[64];
    const int tid = threadIdx.x;
    const int wave = tid >> 6, lane = tid & 63;
    const int row0 = blockIdx.x * 64;
    const int m = lane & 15, t4 = lane >> 4;
    const int lr = lane >> 3, ls = lane & 7;
    const int swz = (ls ^ lr) << 3;
    const int rl4 = lane >> 4;   // Wp2 staging: row within 4-row slab
    const int sl = lane & 15;    // Wp2 staging: physical 16B slot within 256B row

    if (tid < 64) {
        int r = row0 + tid;
        sbatch[tid] = batch[r < N ? r : (N - 1)];
    }

    // issue Wp2 half-0 staging EARLY; it drains under GEMM1's first barrier.
    // wave w stages local cols [w*32, w*32+32): 8 instrs of 4 rows (1KB) each.
#pragma unroll
    for (int it = 0; it < 8; ++it) {
        int c0 = wave * 32 + it * 4;
        int c = c0 + rl4;
        gload16(Wp2t + (size_t)c * 128 + ((sl ^ (c & 15)) << 3), &Wp2s[c0 * 128]);
    }

    // ---- GEMM1: t = relu(Bb@Wp1 + bp1), 64x128, K=256, wave = 32-col slab ----
    f32x4 acc1[4][2];
#pragma unroll
    for (int i = 0; i < 4; ++i)
#pragma unroll
        for (int j = 0; j < 2; ++j) acc1[i][j] = (f32x4)0.f;

    for (int k0 = 0; k0 < 256; k0 += 64) {
#pragma unroll
        for (int i = 0; i < 2; ++i) {
            int rr = wave * 16 + i * 8;
            int gr = row0 + rr + lr; if (gr > N - 1) gr = N - 1;
            gload16(Bb + (size_t)gr * 256 + k0 + swz, &Bbs[rr * 64]);
        }
#pragma unroll
        for (int i = 0; i < 4; ++i) {
            int cc = wave * 32 + i * 8;
            gload16(Wp1t + (size_t)(cc + lr) * 256 + k0 + swz, &Wp1s[cc * 64]);
        }
        __syncthreads();  // drains vmcnt(0) (incl. Wp2 half-0 preload on first pass)
#pragma unroll
        for (int h = 0; h < 2; ++h) {
            const int slot = h * 4 + t4;
            bf16x8 aB[4], bW[2];
#pragma unroll
            for (int i = 0; i < 4; ++i) {
                int r = 16 * i + m;
                aB[i] = *(bf16x8*)&Bbs[r * 64 + ((slot ^ (r & 7)) << 3)];
            }
#pragma unroll
            for (int j = 0; j < 2; ++j) {
                int c = wave * 32 + 16 * j + m;
                bW[j] = *(bf16x8*)&Wp1s[c * 64 + ((slot ^ (c & 7)) << 3)];
            }
#pragma unroll
            for (int i = 0; i < 4; ++i)
#pragma unroll
                for (int j = 0; j < 2; ++j)
                    acc1[i][j] = __builtin_amdgcn_mfma_f32_16x16x32_bf16(aB[i], bW[j], acc1[i][j], 0, 0, 0);
        }
        __syncthreads();
    }

    // GEMM1 epilogue -> Ts (bf16, relu+bias), swizzled 16-slot rows
    const int rq = t4 * 4;
#pragma unroll
    for (int j = 0; j < 2; ++j) {
        int col = wave * 32 + 16 * j + m;
        float bv = bp1[col];
#pragma unroll
        for (int i = 0; i < 4; ++i)
#pragma unroll
            for (int g = 0; g < 4; ++g) {
                int r = 16 * i + rq + g;
                float v = fmaxf(acc1[i][j][g] + bv, 0.f);
                Ts[r * 128 + (((col >> 3) ^ (r & 15)) << 3) + (col & 7)] = (short)f2bf(v);
            }
    }
    __syncthreads();

    // ---- GEMM2 + pool, two 128-col halves:  pat = relu(t@Wp2 + bp2) ----
    const int g0 = sbatch[0];
    const int g1 = sbatch[63];
    for (int hh = 0; hh < 2; ++hh) {
        if (hh == 1) {
            __syncthreads();  // all waves done reading Wp2s half-0
#pragma unroll
            for (int it = 0; it < 8; ++it) {
                int c0 = wave * 32 + it * 4;
                int c = c0 + rl4;
                gload16(Wp2t + (size_t)(128 + c) * 128 + ((sl ^ (c & 15)) << 3), &Wp2s[c0 * 128]);
            }
            __syncthreads();  // drain half-1 DMA
        }

        f32x4 acc2[4][2];
#pragma unroll
        for (int i = 0; i < 4; ++i)
#pragma unroll
            for (int j = 0; j < 2; ++j) acc2[i][j] = (f32x4)0.f;

#pragma unroll
        for (int sl4 = 0; sl4 < 4; ++sl4) {
            const int s16 = sl4 * 4 + t4;
            bf16x8 af[4], bf[2];
#pragma unroll
            for (int i = 0; i < 4; ++i) {
                int r = 16 * i + m;
                af[i] = *(bf16x8*)&Ts[r * 128 + ((s16 ^ (r & 15)) << 3)];
            }
#pragma unroll
            for (int j = 0; j < 2; ++j) {
                int cl = wave * 32 + 16 * j + m;
                bf[j] = *(bf16x8*)&Wp2s[cl * 128 + ((s16 ^ (cl & 15)) << 3)];
            }
#pragma unroll
            for (int i = 0; i < 4; ++i)
#pragma unroll
                for (int j = 0; j < 2; ++j)
                    acc2[i][j] = __builtin_amdgcn_mfma_f32_16x16x32_bf16(af[i], bf[j], acc2[i][j], 0, 0, 0);
        }

        // pooled epilogue for this half's columns
        for (int g = g0; g <= g1; ++g) {
#pragma unroll
            for (int j = 0; j < 2; ++j) {
                int col = hh * 128 + wave * 32 + 16 * j + m;
                float bv = bp2[col];
                float s = 0.f;
#pragma unroll
                for (int i = 0; i < 4; ++i)
#pragma unroll
                    for (int q = 0; q < 4; ++q) {
                        int rl = 16 * i + rq + q;
                        bool ok = (sbatch[rl] == g) && (row0 + rl < N);
                        float v = fmaxf(acc2[i][j][q] + bv, 0.f);
                        s += ok ? v : 0.f;
                    }
                s += __shfl_down(s, 32, 64);
                s += __shfl_down(s, 16, 64);
                if (lane < 16) atomicAdd(&pesum[(size_t)g * 256 + hh * 128 + wave * 32 + 16 * j + lane], s);
            }
        }
    }
}

// ---------------- pooling helpers ----------------
__global__ void k_ranges(const int* __restrict__ batch, int N, int B, int* __restrict__ start,
                         float* __restrict__ countsf) {
    int b = threadIdx.x;
    if (b <= B) {
        int lo = 0, hi = N;
        while (lo < hi) {
            int mid = (lo + hi) >> 1;
            if (batch[mid] < b) lo = mid + 1; else hi = mid;
        }
        start[b] = lo;
    }
    __syncthreads();
    if (b < B) {
        int cnt = start[b + 1] - start[b];
        countsf[b] = (float)(cnt > 0 ? cnt : 1);
    }
}

// finalize pools + assemble comb in one pass
__global__ __launch_bounds__(256) void k_fin_comb(const float* __restrict__ gesum, const float* __restrict__ pesum,
                                                  const float* __restrict__ countsf,
                                                  const float* __restrict__ temb, const int* __restrict__ tidx,
                                                  float* __restrict__ comb) {
    int b = blockIdx.x, t = threadIdx.x;
    float inv = 1.0f / countsf[b];
    float* o = comb + (size_t)b * 1280;
    o[t] = gesum[(size_t)b * 256 + t] * inv;
    o[768 + t] = temb[(size_t)tidx[b] * 256 + t];
    o[1024 + t] = pesum[(size_t)b * 256 + t] * inv;
}

// ---------------- head: parallel fp32 dense layer ----------------
__global__ __launch_bounds__(256) void k_dense(const float* __restrict__ vin, int vs,
                                               const float* __restrict__ W, const float* __restrict__ bias,
                                               float* __restrict__ out, int os, int oo,
                                               int K, int M, int relu) {
    const int b = blockIdx.y;
    const int wave = threadIdx.x >> 6, lane = threadIdx.x & 63;
    const int c = blockIdx.x * 64 + lane;
    const float* vrow = vin + (size_t)b * vs;
    float acc = 0.f;
    int k = wave;
    for (; k + 28 < K; k += 32) {
#pragma unroll
        for (int u = 0; u < 8; ++u)
            acc += vrow[k + 4 * u] * W[(size_t)(k + 4 * u) * M + c];
    }
    for (; k < K; k += 4)
        acc += vrow[k] * W[(size_t)k * M + c];
    __shared__ float red[4][64];
    red[wave][lane] = acc;
    __syncthreads();
    if (wave == 0) {
        float s = red[0][lane] + red[1][lane] + red[2][lane] + red[3][lane] + bias[c];
        if (relu) s = fmaxf(s, 0.f);
        out[(size_t)b * os + oo + c] = s;
    }
}

__global__ __launch_bounds__(256) void k_heads_small(const float* __restrict__ fused,
                                                     const float* __restrict__ Wg, const float* __restrict__ bg,
                                                     const float* __restrict__ Wtp, const float* __restrict__ btp,
                                                     float* __restrict__ out_logits, float* __restrict__ out_tp,
                                                     int NG) {
    __shared__ float lf[256];
    int b = blockIdx.x, tid = threadIdx.x;
    int wave = tid >> 6, lane = tid & 63;
    lf[tid] = fused[(size_t)b * 256 + tid];
    __syncthreads();
    for (int c = wave; c < NG; c += 4) {
        float s = 0.f;
#pragma unroll
        for (int k = lane; k < 256; k += 64) s += lf[k] * Wg[(size_t)k * NG + c];
#pragma unroll
        for (int off = 32; off > 0; off >>= 1) s += __shfl_down(s, off, 64);
        if (lane == 0) out_logits[(size_t)b * NG + c] = s + bg[c];
    }
    if (wave == 0) {
        float s = 0.f;
#pragma unroll
        for (int k = lane; k < 256; k += 64) s += lf[k] * Wtp[k];
#pragma unroll
        for (int off = 32; off > 0; off >>= 1) s += __shfl_down(s, off, 64);
        if (lane == 0) out_tp[b] = s + btp[0];
    }
}

// ---------------- host launch ----------------
extern "C" void kernel_launch(void* const* d_in, const int* in_sizes, int n_in,
                              void* d_out, int out_size, void* d_ws, size_t ws_size,
                              hipStream_t stream) {
    const float* x   = (const float*)d_in[0];
    const int* ei    = (const int*)d_in[1];
    const int* batch = (const int*)d_in[2];
    const float* sf  = (const float*)d_in[3];
    const float* tf  = (const float*)d_in[4];
    const int* tidx  = (const int*)d_in[5];
    const float* temb = (const float*)d_in[6];
    const float *Ws1 = (const float*)d_in[7],  *bs1 = (const float*)d_in[8];
    const float *Ws2 = (const float*)d_in[9],  *bs2 = (const float*)d_in[10];
    const float *Wc1 = (const float*)d_in[11], *bc1 = (const float*)d_in[12];
    const float *Wc2 = (const float*)d_in[13], *bc2 = (const float*)d_in[14];
    const float *Wc3 = (const float*)d_in[15], *bc3 = (const float*)d_in[16];
    const float *Wd1 = (const float*)d_in[17], *bd1 = (const float*)d_in[18];
    const float *Wd2 = (const float*)d_in[19], *bd2 = (const float*)d_in[20];
    const float *Wd3 = (const float*)d_in[21], *bd3 = (const float*)d_in[22];
    const float *Wt1 = (const float*)d_in[23], *bt1 = (const float*)d_in[24];
    const float *Wt2 = (const float*)d_in[25], *bt2 = (const float*)d_in[26];
    const float *Wp1 = (const float*)d_in[27], *bp1 = (const float*)d_in[28];
    const float *Wp2 = (const float*)d_in[29], *bp2 = (const float*)d_in[30];
    const float *Wf1 = (const float*)d_in[31], *bf1 = (const float*)d_in[32];
    const float *Wf2 = (const float*)d_in[33], *bf2 = (const float*)d_in[34];
    const float *Wg  = (const float*)d_in[35], *bg  = (const float*)d_in[36];
    const float *Wtp = (const float*)d_in[37], *btp = (const float*)d_in[38];

    const int N = in_sizes[2];
    const int E = in_sizes[1] / 2;
    const int B = in_sizes[5];
    const int DIN = in_sizes[0] / N;       // 128
    const int DS = in_sizes[3] / B;        // 1024
    const int NG = in_sizes[36];           // 20
    const int* src = ei;
    const int* dst = ei + E;

    // ---- workspace layout ----
    char* w = (char*)d_ws;
    ushort* A   = (ushort*)w;              w += (size_t)N * 256 * 2;
    ushort* Bb  = (ushort*)w;              w += (size_t)N * 256 * 2;
    ushort* xh  = (ushort*)w;              w += (size_t)N * 128 * 2;
    ushort* Wc1t = (ushort*)w;             w += 128 * 256 * 2;
    ushort* Wd1t = (ushort*)w;             w += 128 * 256 * 2;
    ushort* Wc2t = (ushort*)w;             w += 256 * 256 * 2;
    ushort* Wd2t = (ushort*)w;             w += 256 * 256 * 2;
    ushort* Wc3t = (ushort*)w;             w += 256 * 256 * 2;
    ushort* Wd3t = (ushort*)w;             w += 256 * 256 * 2;
    ushort* Wp1t = (ushort*)w;             w += 256 * 128 * 2;
    ushort* Wp2t = (ushort*)w;             w += 128 * 256 * 2;
    int* esrc   = (int*)w;                 w += (size_t)E * 4;
    float* ewt  = (float*)w;               w += (size_t)E * 4;
    int* cnt    = (int*)w;                 w += (size_t)N * 4;
    int* part   = (int*)w;                 w += (size_t)N * 4;
    int* rowptr = (int*)w;                 w += (size_t)(N + 1) * 4;
    int* fill   = (int*)w;                 w += (size_t)N * 4;
    int* bsums  = (int*)w;                 w += 1024 * 4;
    float* dinv = (float*)w;               w += (size_t)N * 4;
    float* selfw = (float*)w;              w += (size_t)N * 4;
    int* startp = (int*)w;                 w += (B + 1) * 4;
    float* countsf = (float*)w;            w += B * 4;
    float* ge = (float*)w;                 w += B * 256 * 4;   // ge then pe contiguous (zeroed together)
    float* pe = (float*)w;                 w += B * 256 * 4;
    float* s1buf = (float*)w;              w += B * 256 * 4;
    float* t1buf = (float*)w;              w += B * 128 * 4;
    float* comb = (float*)w;               w += B * 1280 * 4;
    float* fh = (float*)w;                 w += B * 512 * 4;

    float* out_fused = (float*)d_out;                 // B x 256
    float* out_logits = out_fused + (size_t)B * H;    // B x NG
    float* out_tp = out_logits + (size_t)B * NG;      // B x 1

    dim3 blk(256);
    const int nbN = (N + 255) / 256;
    const int nbE = (E + 255) / 256;

    // ---- CSR build ----
    k_zero2_i<<<dim3(nbN), blk, 0, stream>>>(cnt, fill, N);
    k_count_deg_i<<<dim3(nbE), blk, 0, stream>>>(dst, cnt, E);
    k_scan1<<<dim3(nbN), blk, 0, stream>>>(cnt, part, bsums, N);
    k_scan2<<<dim3(1), dim3(1024), 0, stream>>>(bsums, nbN);
    k_scan3<<<dim3(nbN), blk, 0, stream>>>(part, bsums, cnt, rowptr, dinv, selfw, N);
    k_scatter<<<dim3(nbE), blk, 0, stream>>>(src, dst, dinv, rowptr, fill, esrc, ewt, E);

    // ---- batched conversions + pooling prep ----
    {
        long nx = (long)N * DIN;
        long tot = nx + 2L * DIN * 256 + 4L * 65536 + 2L * 32768;
        k_prep<<<dim3((unsigned)((tot + 255) / 256)), blk, 0, stream>>>(
            x, xh, nx, DIN, Wc1, Wc1t, Wd1, Wd1t, Wc2, Wc2t, Wd2, Wd2t,
            Wc3, Wc3t, Wd3, Wd3t, Wp1, Wp1t, Wp2, Wp2t);
        k_ranges<<<dim3(1), dim3(128), 0, stream>>>(batch, N, B, startp, countsf);
        k_zero_f<<<dim3((2 * B * 256 + 255) / 256), blk, 0, stream>>>(ge, 2 * B * 256);
    }

    const int ngb4 = (N + 3) / 4;     // gather_b4: 4 nodes per 256-thread block (1/wave)
    const int ngb2 = (N + 15) / 16;   // gather_b2: 16 nodes per block (4/wave)
    const int nfb = (N + 63) / 64;

    // ---- static + temporal encoders ----
    k_dense<<<dim3(4, B), blk, 0, stream>>>(sf, DS, Ws1, bs1, s1buf, 256, 0, DS, 256, 1);
    k_dense<<<dim3(4, B), blk, 0, stream>>>(s1buf, 256, Ws2, bs2, comb, 1280, 256, 256, 256, 0);
    k_dense<<<dim3(2, B), blk, 0, stream>>>(tf, 5, Wt1, bt1, t1buf, 128, 0, 5, 128, 1);
    k_dense<<<dim3(4, B), blk, 0, stream>>>(t1buf, 128, Wt2, bt2, comb, 1280, 512, 128, 256, 0);

    // ---- 3 GCN layers (layer 3 fuses the ge mean-pool numerator) ----
    k_gather_b2<<<dim3(ngb2), blk, 0, stream>>>(xh, rowptr, esrc, ewt, selfw, A, N, 128, 128);
    k_fused_mfma<<<dim3(nfb), blk, 0, stream>>>(A, xh, Wc1t, Wd1t, bc1, bd1, Bb, N, 128, 128, 128, batch, ge, 0);
    k_gather_b4<<<dim3(ngb4), blk, 0, stream>>>(Bb, rowptr, esrc, ewt, selfw, A, N, 256, 256);
    k_fused_mfma<<<dim3(nfb), blk, 0, stream>>>(A, Bb, Wc2t, Wd2t, bc2, bd2, A, N, 256, 256, 256, batch, ge, 0);
    k_gather_b4<<<dim3(ngb4), blk, 0, stream>>>(A, rowptr, esrc, ewt, selfw, Bb, N, 256, 256);
    k_fused_mfma<<<dim3(nfb), blk, 0, stream>>>(Bb, A, Wc3t, Wd3t, bc3, bd3, Bb, N, 256, 256, 256, batch, ge, 1);

    // ---- fused pattern chain: p1 + p2 + pe-pool in one kernel ----
    k_pat_fused<<<dim3(nfb), blk, 0, stream>>>(Bb, Wp1t, Wp2t, bp1, bp2, batch, pe, N);
    k_fin_comb<<<dim3(B), blk, 0, stream>>>(ge, pe, countsf, temb, tidx, comb);

    // ---- head ----
    k_dense<<<dim3(8, B), blk, 0, stream>>>(comb, 1280, Wf1, bf1, fh, 512, 0, 1280, 512, 1);
    k_dense<<<dim3(4, B), blk, 0, stream>>>(fh, 512, Wf2, bf2, out_fused, 256, 0, 512, 256, 0);
    k_heads_small<<<dim3(B), blk, 0, stream>>>(out_fused, Wg, bg, Wtp, btp, out_logits, out_tp, NG);
}

// Round 8
// 862.730 us; speedup vs baseline: 1.0041x; 1.0041x over previous
//
#include <hip/hip_runtime.h>

#define H 256

typedef __attribute__((ext_vector_type(8))) short bf16x8;
typedef __attribute__((ext_vector_type(4))) float f32x4;

__device__ __forceinline__ float b2f(ushort h) {
    return __uint_as_float(((unsigned)h) << 16);
}
__device__ __forceinline__ float b2f_lo(unsigned u) {  // low bf16 of packed pair
    return __uint_as_float(u << 16);
}
__device__ __forceinline__ float b2f_hi(unsigned u) {  // high bf16 of packed pair
    return __uint_as_float(u & 0xffff0000u);
}
__device__ __forceinline__ ushort f2bf(float f) {
    unsigned u = __float_as_uint(f);
    unsigned r = (u + 0x7FFF + ((u >> 16) & 1)) >> 16;  // RNE
    return (ushort)r;
}
__device__ __forceinline__ unsigned pack2bf(float lo, float hi) {
    return (unsigned)f2bf(lo) | ((unsigned)f2bf(hi) << 16);
}

// async global->LDS DMA, 16B per lane, wave-uniform LDS base + lane*16 (HW-defined)
__device__ __forceinline__ void gload16(const ushort* g, const short* l) {
    __builtin_amdgcn_global_load_lds(
        (const __attribute__((address_space(1))) void*)(const void*)g,
        (__attribute__((address_space(3))) void*)(void*)l, 16, 0, 0);
}

// ---------------- CSR build ----------------
__global__ __launch_bounds__(256) void k_zero2_i(int* p, int* q, int n) {
    int i = blockIdx.x * 256 + threadIdx.x;
    if (i < n) { p[i] = 0; q[i] = 0; }
}

__global__ __launch_bounds__(256) void k_zero_f(float* p, int n) {
    int i = blockIdx.x * 256 + threadIdx.x;
    if (i < n) p[i] = 0.f;
}

__global__ __launch_bounds__(256) void k_count_deg_i(const int* __restrict__ dst, int* cnt, int E) {
    int i = blockIdx.x * 256 + threadIdx.x;
    if (i < E) atomicAdd(&cnt[dst[i]], 1);
}

__global__ __launch_bounds__(256) void k_scan1(const int* __restrict__ cnt, int* __restrict__ partial,
                                               int* __restrict__ bsums, int N) {
    __shared__ int s[256];
    int t = threadIdx.x;
    int idx = blockIdx.x * 256 + t;
    int v = idx < N ? cnt[idx] : 0;
    s[t] = v;
    __syncthreads();
    for (int off = 1; off < 256; off <<= 1) {
        int add = (t >= off) ? s[t - off] : 0;
        __syncthreads();
        s[t] += add;
        __syncthreads();
    }
    if (idx < N) partial[idx] = s[t];
    if (t == 255) bsums[blockIdx.x] = s[t];
}

__global__ __launch_bounds__(1024) void k_scan2(int* bsums, int nb) {
    __shared__ int s[1024];
    int t = threadIdx.x;
    s[t] = (t < nb) ? bsums[t] : 0;
    __syncthreads();
    for (int off = 1; off < 1024; off <<= 1) {
        int add = (t >= off) ? s[t - off] : 0;
        __syncthreads();
        s[t] += add;
        __syncthreads();
    }
    if (t < nb) bsums[t] = s[t];
}

// rowptr + dinv/selfw in one pass
__global__ __launch_bounds__(256) void k_scan3(const int* __restrict__ partial, const int* __restrict__ bsums,
                                               const int* __restrict__ cnt,
                                               int* __restrict__ rowptr, float* __restrict__ dinv,
                                               float* __restrict__ selfw, int N) {
    int idx = blockIdx.x * 256 + threadIdx.x;
    if (idx < N) {
        int off = blockIdx.x > 0 ? bsums[blockIdx.x - 1] : 0;
        rowptr[idx + 1] = partial[idx] + off;
        if (idx == 0) rowptr[0] = 0;
        float d = 1.0f + (float)cnt[idx];
        dinv[idx] = rsqrtf(d);
        selfw[idx] = 1.0f / d;
    }
}

__global__ __launch_bounds__(256) void k_scatter(const int* __restrict__ src, const int* __restrict__ dst,
                                                 const float* __restrict__ dinv, const int* __restrict__ rowptr,
                                                 int* __restrict__ fill, int* __restrict__ esrc,
                                                 float* __restrict__ ewt, int E) {
    int e = blockIdx.x * 256 + threadIdx.x;
    if (e >= E) return;
    int s = src[e], d = dst[e];
    int pos = rowptr[d] + atomicAdd(&fill[d], 1);
    esrc[pos] = s;
    ewt[pos] = dinv[s] * dinv[d];
}

// ---------------- batched conversions: x->bf16 + all 8 weight transposes ----------------
__device__ __forceinline__ void tcvt_one(long i, const float* __restrict__ W, ushort* __restrict__ Wt,
                                         int K, int M) {
    int k = (int)(i / M), m = (int)(i - (long)k * M);
    Wt[(size_t)m * K + k] = f2bf(W[(size_t)k * M + m]);
}

__global__ __launch_bounds__(256) void k_prep(
    const float* __restrict__ x, ushort* __restrict__ xh, long nx, int DIN,
    const float* __restrict__ Wc1, ushort* Wc1t, const float* __restrict__ Wd1, ushort* Wd1t,
    const float* __restrict__ Wc2, ushort* Wc2t, const float* __restrict__ Wd2, ushort* Wd2t,
    const float* __restrict__ Wc3, ushort* Wc3t, const float* __restrict__ Wd3, ushort* Wd3t,
    const float* __restrict__ Wp1, ushort* Wp1t, const float* __restrict__ Wp2, ushort* Wp2t) {
    long i = (long)blockIdx.x * 256 + threadIdx.x;
    if (i < nx) { xh[i] = f2bf(x[i]); return; }
    i -= nx;
    long n1 = (long)DIN * 256;
    if (i < n1) { tcvt_one(i, Wc1, Wc1t, DIN, 256); return; }
    i -= n1;
    if (i < n1) { tcvt_one(i, Wd1, Wd1t, DIN, 256); return; }
    i -= n1;
    if (i < 65536) { tcvt_one(i, Wc2, Wc2t, 256, 256); return; }
    i -= 65536;
    if (i < 65536) { tcvt_one(i, Wd2, Wd2t, 256, 256); return; }
    i -= 65536;
    if (i < 65536) { tcvt_one(i, Wc3, Wc3t, 256, 256); return; }
    i -= 65536;
    if (i < 65536) { tcvt_one(i, Wd3, Wd3t, 256, 256); return; }
    i -= 65536;
    if (i < 32768) { tcvt_one(i, Wp1, Wp1t, 256, 128); return; }
    i -= 32768;
    if (i < 32768) { tcvt_one(i, Wp2, Wp2t, 128, 256); return; }
}

// ---------------- CSR gather (bf16 in, fp32 acc, bf16 out) ----------------
// b4: 1 node per wave, ushort4/lane (proven fastest variant, round-2: 83.0us).
// Round-3 A/B showed the gather is service-rate-bound (random 512B granules), not
// latency/issue-bound: doubling bytes/instr and in-flight bytes changed nothing.
__global__ __launch_bounds__(256) void k_gather_b4(const ushort* __restrict__ xin, const int* __restrict__ rowptr,
                                                   const int* __restrict__ esrc, const float* __restrict__ ewt,
                                                   const float* __restrict__ selfw, ushort* __restrict__ p,
                                                   int N, int SX, int SP) {
    int node = blockIdx.x * 4 + (threadIdx.x >> 6);
    if (node >= N) return;
    int c = (threadIdx.x & 63) << 2;
    ushort4 h = *(const ushort4*)(xin + (size_t)node * SX + c);
    float sw = selfw[node];
    float a0 = b2f(h.x) * sw, a1 = b2f(h.y) * sw, a2 = b2f(h.z) * sw, a3 = b2f(h.w) * sw;
    int j = rowptr[node], r1 = rowptr[node + 1];
    for (; j + 3 < r1; j += 4) {
        int s0 = esrc[j], s1 = esrc[j + 1], s2 = esrc[j + 2], s3 = esrc[j + 3];
        float w0 = ewt[j], w1 = ewt[j + 1], w2 = ewt[j + 2], w3 = ewt[j + 3];
        ushort4 v0 = *(const ushort4*)(xin + (size_t)s0 * SX + c);
        ushort4 v1 = *(const ushort4*)(xin + (size_t)s1 * SX + c);
        ushort4 v2 = *(const ushort4*)(xin + (size_t)s2 * SX + c);
        ushort4 v3 = *(const ushort4*)(xin + (size_t)s3 * SX + c);
        a0 += b2f(v0.x) * w0 + b2f(v1.x) * w1 + b2f(v2.x) * w2 + b2f(v3.x) * w3;
        a1 += b2f(v0.y) * w0 + b2f(v1.y) * w1 + b2f(v2.y) * w2 + b2f(v3.y) * w3;
        a2 += b2f(v0.z) * w0 + b2f(v1.z) * w1 + b2f(v2.z) * w2 + b2f(v3.z) * w3;
        a3 += b2f(v0.w) * w0 + b2f(v1.w) * w1 + b2f(v2.w) * w2 + b2f(v3.w) * w3;
    }
    for (; j < r1; ++j) {
        int s0 = esrc[j];
        float w0 = ewt[j];
        ushort4 v0 = *(const ushort4*)(xin + (size_t)s0 * SX + c);
        a0 += b2f(v0.x) * w0; a1 += b2f(v0.y) * w0; a2 += b2f(v0.z) * w0; a3 += b2f(v0.w) * w0;
    }
    ushort4 o;
    o.x = f2bf(a0); o.y = f2bf(a1); o.z = f2bf(a2); o.w = f2bf(a3);
    *(ushort4*)(p + (size_t)node * SP + c) = o;
}

// 4 nodes per wave (16-lane group per node), 16B per lane covers a 256B (128-col) row.
__global__ __launch_bounds__(256) void k_gather_b2(const ushort* __restrict__ xin, const int* __restrict__ rowptr,
                                                   const int* __restrict__ esrc, const float* __restrict__ ewt,
                                                   const float* __restrict__ selfw, ushort* __restrict__ p,
                                                   int N, int SX, int SP) {
    int node = blockIdx.x * 16 + (threadIdx.x >> 4);
    bool act = node < N;
    int nn = act ? node : N - 1;
    int c = (threadIdx.x & 15) << 3;  // 8 cols (16B) per lane, 16 lanes = 128 cols
    uint4 hv = *(const uint4*)(xin + (size_t)nn * SX + c);
    float sw = selfw[nn];
    float a0 = b2f_lo(hv.x) * sw, a1 = b2f_hi(hv.x) * sw;
    float a2 = b2f_lo(hv.y) * sw, a3 = b2f_hi(hv.y) * sw;
    float a4 = b2f_lo(hv.z) * sw, a5 = b2f_hi(hv.z) * sw;
    float a6 = b2f_lo(hv.w) * sw, a7 = b2f_hi(hv.w) * sw;
    int j = act ? rowptr[nn] : 0, r1 = act ? rowptr[nn + 1] : 0;
    for (; j + 3 < r1; j += 4) {
        int s0 = esrc[j], s1 = esrc[j + 1], s2 = esrc[j + 2], s3 = esrc[j + 3];
        float w0 = ewt[j], w1 = ewt[j + 1], w2 = ewt[j + 2], w3 = ewt[j + 3];
        uint4 v0 = *(const uint4*)(xin + (size_t)s0 * SX + c);
        uint4 v1 = *(const uint4*)(xin + (size_t)s1 * SX + c);
        uint4 v2 = *(const uint4*)(xin + (size_t)s2 * SX + c);
        uint4 v3 = *(const uint4*)(xin + (size_t)s3 * SX + c);
        a0 += b2f_lo(v0.x) * w0 + b2f_lo(v1.x) * w1 + b2f_lo(v2.x) * w2 + b2f_lo(v3.x) * w3;
        a1 += b2f_hi(v0.x) * w0 + b2f_hi(v1.x) * w1 + b2f_hi(v2.x) * w2 + b2f_hi(v3.x) * w3;
        a2 += b2f_lo(v0.y) * w0 + b2f_lo(v1.y) * w1 + b2f_lo(v2.y) * w2 + b2f_lo(v3.y) * w3;
        a3 += b2f_hi(v0.y) * w0 + b2f_hi(v1.y) * w1 + b2f_hi(v2.y) * w2 + b2f_hi(v3.y) * w3;
        a4 += b2f_lo(v0.z) * w0 + b2f_lo(v1.z) * w1 + b2f_lo(v2.z) * w2 + b2f_lo(v3.z) * w3;
        a5 += b2f_hi(v0.z) * w0 + b2f_hi(v1.z) * w1 + b2f_hi(v2.z) * w2 + b2f_hi(v3.z) * w3;
        a6 += b2f_lo(v0.w) * w0 + b2f_lo(v1.w) * w1 + b2f_lo(v2.w) * w2 + b2f_lo(v3.w) * w3;
        a7 += b2f_hi(v0.w) * w0 + b2f_hi(v1.w) * w1 + b2f_hi(v2.w) * w2 + b2f_hi(v3.w) * w3;
    }
    for (; j < r1; ++j) {
        int s0 = esrc[j];
        float w0 = ewt[j];
        uint4 v0 = *(const uint4*)(xin + (size_t)s0 * SX + c);
        a0 += b2f_lo(v0.x) * w0; a1 += b2f_hi(v0.x) * w0;
        a2 += b2f_lo(v0.y) * w0; a3 += b2f_hi(v0.y) * w0;
        a4 += b2f_lo(v0.z) * w0; a5 += b2f_hi(v0.z) * w0;
        a6 += b2f_lo(v0.w) * w0; a7 += b2f_hi(v0.w) * w0;
    }
    if (act) {
        uint4 o;
        o.x = pack2bf(a0, a1); o.y = pack2bf(a2, a3);
        o.z = pack2bf(a4, a5); o.w = pack2bf(a6, a7);
        *(uint4*)(p + (size_t)node * SP + c) = o;
    }
}

// ---------------- fused dual-GEMM MFMA v3 (REVERTED from v4):  Out = relu(Pm@Wc+bc) + X@Wd+bd --
// v4 (round-7) regressed 77->114us/layer: per-lane global weight loads put ~200cy L2 latency
// inside every MFMA phase (MfmaUtil 8.9%). v3's wave-shared LDS staging batches that latency
// into one pipelined DMA drain per K-step -- proven structure, SQ_LDS_BANK_CONFLICT == 0.
// 64 rows x 256 cols per block, 4 waves, wave = 64-col slab, dual 4x4 acc, BK=64.
// LDS 80KB -> 2 blocks/CU. dopool: layer-3 epilogue accumulates ge; sbatch reuses Ps.
__global__ __launch_bounds__(256, 2) void k_fused_mfma(
    const ushort* __restrict__ Pm, const ushort* __restrict__ X,
    const ushort* __restrict__ Wct, const ushort* __restrict__ Wdt,
    const float* __restrict__ bc, const float* __restrict__ bd,
    ushort* __restrict__ Out, int N, int K, int SP, int SX,
    const int* __restrict__ batch, float* __restrict__ gesum, int dopool) {
    __shared__ __align__(16) short Ps[64 * 64];
    __shared__ __align__(16) short Xs[64 * 64];
    __shared__ __align__(16) short Wcs[256 * 64];
    __shared__ __align__(16) short Wds[256 * 64];
    const int tid = threadIdx.x;
    const int wave = tid >> 6, lane = tid & 63;
    const int row0 = blockIdx.x * 64;

    f32x4 accC[4][4], accD[4][4];
#pragma unroll
    for (int i = 0; i < 4; ++i)
#pragma unroll
        for (int j = 0; j < 4; ++j) { accC[i][j] = (f32x4)0.f; accD[i][j] = (f32x4)0.f; }

    const int lr = lane >> 3;          // staging: row within 8-row slab
    const int ls = lane & 7;           // staging: physical 16B slot within 128B row
    const int swz = (ls ^ lr) << 3;    // pre-swizzled source offset (halves)
    const int m = lane & 15, t4 = lane >> 4;

    for (int k0 = 0; k0 < K; k0 += 64) {
        // inputs: this wave stages rows [wave*16, wave*16+16) of Ps and Xs
#pragma unroll
        for (int i = 0; i < 2; ++i) {
            int rr = wave * 16 + i * 8;
            int gr = row0 + rr + lr; if (gr > N - 1) gr = N - 1;
            gload16(Pm + (size_t)gr * SP + k0 + swz, &Ps[rr * 64]);
            gload16(X + (size_t)gr * SX + k0 + swz, &Xs[rr * 64]);
        }
        // weights: this wave stages its own col block [wave*64, wave*64+64)
#pragma unroll
        for (int i = 0; i < 8; ++i) {
            int cc = wave * 64 + i * 8;
            gload16(Wct + (size_t)(cc + lr) * K + k0 + swz, &Wcs[cc * 64]);
            gload16(Wdt + (size_t)(cc + lr) * K + k0 + swz, &Wds[cc * 64]);
        }
        __syncthreads();  // drains vmcnt(0): all DMA landed

#pragma unroll
        for (int h = 0; h < 2; ++h) {
            const int slot = h * 4 + t4;
            bf16x8 aP[4], aX[4], bC[4], bD[4];
#pragma unroll
            for (int i = 0; i < 4; ++i) {
                int r = 16 * i + m;
                int off = r * 64 + ((slot ^ (r & 7)) << 3);
                aP[i] = *(bf16x8*)&Ps[off];
                aX[i] = *(bf16x8*)&Xs[off];
            }
#pragma unroll
            for (int j = 0; j < 4; ++j) {
                int c = wave * 64 + 16 * j + m;
                int off = c * 64 + ((slot ^ (c & 7)) << 3);
                bC[j] = *(bf16x8*)&Wcs[off];
                bD[j] = *(bf16x8*)&Wds[off];
            }
#pragma unroll
            for (int i = 0; i < 4; ++i)
#pragma unroll
                for (int j = 0; j < 4; ++j) {
                    accC[i][j] = __builtin_amdgcn_mfma_f32_16x16x32_bf16(aP[i], bC[j], accC[i][j], 0, 0, 0);
                    accD[i][j] = __builtin_amdgcn_mfma_f32_16x16x32_bf16(aX[i], bD[j], accD[i][j], 0, 0, 0);
                }
        }
        __syncthreads();  // protect LDS before next K-step's DMA
    }

    // after the last trailing barrier every wave is done with LDS -> Ps region reusable
    int* sb = (int*)Ps;
    if (dopool && tid < 64) {
        int r = row0 + tid;
        sb[tid] = batch[r < N ? r : (N - 1)];
    }

    const int rq = t4 * 4;
#pragma unroll
    for (int j = 0; j < 4; ++j) {
        int col = wave * 64 + 16 * j + m;
        float bcv = bc[col], bdv = bd[col];
#pragma unroll
        for (int i = 0; i < 4; ++i)
#pragma unroll
            for (int g = 0; g < 4; ++g) {
                int row = row0 + 16 * i + rq + g;
                if (row < N) {
                    float v = fmaxf(accC[i][j][g] + bcv, 0.f) + accD[i][j][g] + bdv;
                    Out[(size_t)row * 256 + col] = f2bf(v);
                }
            }
    }

    if (dopool) {
        __syncthreads();
        const int g0 = sb[0], g1 = sb[63];
        for (int g = g0; g <= g1; ++g) {
#pragma unroll
            for (int j = 0; j < 4; ++j) {
                int col = wave * 64 + 16 * j + m;
                float bcv = bc[col], bdv = bd[col];
                float s = 0.f;
#pragma unroll
                for (int i = 0; i < 4; ++i)
#pragma unroll
                    for (int q = 0; q < 4; ++q) {
                        int rl = 16 * i + rq + q;
                        bool ok = (sb[rl] == g) && (row0 + rl < N);
                        float v = fmaxf(accC[i][j][q] + bcv, 0.f) + accD[i][j][q] + bdv;
                        s += ok ? v : 0.f;
                    }
                s += __shfl_down(s, 32, 64);
                s += __shfl_down(s, 16, 64);
                if (lane < 16) atomicAdd(&gesum[(size_t)g * 256 + wave * 64 + 16 * j + lane], s);
            }
        }
    }
}

// ---------------- fused pattern chain v2: pe += pool(relu(relu(Bb@Wp1+bp1)@Wp2+bp2)) ----------
// GEMM2 runs in two 128-col halves through ONE 32KB Wp2 staging buffer. Half-0's staging is
// issued at kernel entry (drained for free by GEMM1's first barrier); only half-1's 32KB stage is
// exposed, overlapped by the co-resident block. LDS = 32+16+8+16KB + sbatch ~= 72.3KB -> 2 blocks/CU.
__global__ __launch_bounds__(256, 2) void k_pat_fused(
    const ushort* __restrict__ Bb, const ushort* __restrict__ Wp1t, const ushort* __restrict__ Wp2t,
    const float* __restrict__ bp1, const float* __restrict__ bp2,
    const int* __restrict__ batch, float* __restrict__ pesum, int N) {
    __shared__ __align__(16) short Wp2s[128 * 128];  // 32KB: one 128-col half of Wp2 at a time
    __shared__ __align__(16) short Wp1s[128 * 64];   // 16KB
    __shared__ __align__(16) short Bbs[64 * 64];     // 8KB
    __shared__ __align__(16) short Ts[64 * 128];     // 16KB
    __shared__ int sbatch[64];
    const int tid = threadIdx.x;
    const int wave = tid >> 6, lane = tid & 63;
    const int row0 = blockIdx.x * 64;
    const int m = lane & 15, t4 = lane >> 4;
    const int lr = lane >> 3, ls = lane & 7;
    const int swz = (ls ^ lr) << 3;
    const int rl4 = lane >> 4;   // Wp2 staging: row within 4-row slab
    const int sl = lane & 15;    // Wp2 staging: physical 16B slot within 256B row

    if (tid < 64) {
        int r = row0 + tid;
        sbatch[tid] = batch[r < N ? r : (N - 1)];
    }

    // issue Wp2 half-0 staging EARLY; it drains under GEMM1's first barrier.
    // wave w stages local cols [w*32, w*32+32): 8 instrs of 4 rows (1KB) each.
#pragma unroll
    for (int it = 0; it < 8; ++it) {
        int c0 = wave * 32 + it * 4;
        int c = c0 + rl4;
        gload16(Wp2t + (size_t)c * 128 + ((sl ^ (c & 15)) << 3), &Wp2s[c0 * 128]);
    }

    // ---- GEMM1: t = relu(Bb@Wp1 + bp1), 64x128, K=256, wave = 32-col slab ----
    f32x4 acc1[4][2];
#pragma unroll
    for (int i = 0; i < 4; ++i)
#pragma unroll
        for (int j = 0; j < 2; ++j) acc1[i][j] = (f32x4)0.f;

    for (int k0 = 0; k0 < 256; k0 += 64) {
#pragma unroll
        for (int i = 0; i < 2; ++i) {
            int rr = wave * 16 + i * 8;
            int gr = row0 + rr + lr; if (gr > N - 1) gr = N - 1;
            gload16(Bb + (size_t)gr * 256 + k0 + swz, &Bbs[rr * 64]);
        }
#pragma unroll
        for (int i = 0; i < 4; ++i) {
            int cc = wave * 32 + i * 8;
            gload16(Wp1t + (size_t)(cc + lr) * 256 + k0 + swz, &Wp1s[cc * 64]);
        }
        __syncthreads();  // drains vmcnt(0) (incl. Wp2 half-0 preload on first pass)
#pragma unroll
        for (int h = 0; h < 2; ++h) {
            const int slot = h * 4 + t4;
            bf16x8 aB[4], bW[2];
#pragma unroll
            for (int i = 0; i < 4; ++i) {
                int r = 16 * i + m;
                aB[i] = *(bf16x8*)&Bbs[r * 64 + ((slot ^ (r & 7)) << 3)];
            }
#pragma unroll
            for (int j = 0; j < 2; ++j) {
                int c = wave * 32 + 16 * j + m;
                bW[j] = *(bf16x8*)&Wp1s[c * 64 + ((slot ^ (c & 7)) << 3)];
            }
#pragma unroll
            for (int i = 0; i < 4; ++i)
#pragma unroll
                for (int j = 0; j < 2; ++j)
                    acc1[i][j] = __builtin_amdgcn_mfma_f32_16x16x32_bf16(aB[i], bW[j], acc1[i][j], 0, 0, 0);
        }
        __syncthreads();
    }

    // GEMM1 epilogue -> Ts (bf16, relu+bias), swizzled 16-slot rows
    const int rq = t4 * 4;
#pragma unroll
    for (int j = 0; j < 2; ++j) {
        int col = wave * 32 + 16 * j + m;
        float bv = bp1[col];
#pragma unroll
        for (int i = 0; i < 4; ++i)
#pragma unroll
            for (int g = 0; g < 4; ++g) {
                int r = 16 * i + rq + g;
                float v = fmaxf(acc1[i][j][g] + bv, 0.f);
                Ts[r * 128 + (((col >> 3) ^ (r & 15)) << 3) + (col & 7)] = (short)f2bf(v);
            }
    }
    __syncthreads();

    // ---- GEMM2 + pool, two 128-col halves:  pat = relu(t@Wp2 + bp2) ----
    const int g0 = sbatch[0];
    const int g1 = sbatch[63];
    for (int hh = 0; hh < 2; ++hh) {
        if (hh == 1) {
            __syncthreads();  // all waves done reading Wp2s half-0
#pragma unroll
            for (int it = 0; it < 8; ++it) {
                int c0 = wave * 32 + it * 4;
                int c = c0 + rl4;
                gload16(Wp2t + (size_t)(128 + c) * 128 + ((sl ^ (c & 15)) << 3), &Wp2s[c0 * 128]);
            }
            __syncthreads();  // drain half-1 DMA
        }

        f32x4 acc2[4][2];
#pragma unroll
        for (int i = 0; i < 4; ++i)
#pragma unroll
            for (int j = 0; j < 2; ++j) acc2[i][j] = (f32x4)0.f;

#pragma unroll
        for (int sl4 = 0; sl4 < 4; ++sl4) {
            const int s16 = sl4 * 4 + t4;
            bf16x8 af[4], bf[2];
#pragma unroll
            for (int i = 0; i < 4; ++i) {
                int r = 16 * i + m;
                af[i] = *(bf16x8*)&Ts[r * 128 + ((s16 ^ (r & 15)) << 3)];
            }
#pragma unroll
            for (int j = 0; j < 2; ++j) {
                int cl = wave * 32 + 16 * j + m;
                bf[j] = *(bf16x8*)&Wp2s[cl * 128 + ((s16 ^ (cl & 15)) << 3)];
            }
#pragma unroll
            for (int i = 0; i < 4; ++i)
#pragma unroll
                for (int j = 0; j < 2; ++j)
                    acc2[i][j] = __builtin_amdgcn_mfma_f32_16x16x32_bf16(af[i], bf[j], acc2[i][j], 0, 0, 0);
        }

        // pooled epilogue for this half's columns
        for (int g = g0; g <= g1; ++g) {
#pragma unroll
            for (int j = 0; j < 2; ++j) {
                int col = hh * 128 + wave * 32 + 16 * j + m;
                float bv = bp2[col];
                float s = 0.f;
#pragma unroll
                for (int i = 0; i < 4; ++i)
#pragma unroll
                    for (int q = 0; q < 4; ++q) {
                        int rl = 16 * i + rq + q;
                        bool ok = (sbatch[rl] == g) && (row0 + rl < N);
                        float v = fmaxf(acc2[i][j][q] + bv, 0.f);
                        s += ok ? v : 0.f;
                    }
                s += __shfl_down(s, 32, 64);
                s += __shfl_down(s, 16, 64);
                if (lane < 16) atomicAdd(&pesum[(size_t)g * 256 + hh * 128 + wave * 32 + 16 * j + lane], s);
            }
        }
    }
}

// ---------------- pooling helpers ----------------
__global__ void k_ranges(const int* __restrict__ batch, int N, int B, int* __restrict__ start,
                         float* __restrict__ countsf) {
    int b = threadIdx.x;
    if (b <= B) {
        int lo = 0, hi = N;
        while (lo < hi) {
            int mid = (lo + hi) >> 1;
            if (batch[mid] < b) lo = mid + 1; else hi = mid;
        }
        start[b] = lo;
    }
    __syncthreads();
    if (b < B) {
        int cnt = start[b + 1] - start[b];
        countsf[b] = (float)(cnt > 0 ? cnt : 1);
    }
}

// finalize pools + assemble comb in one pass
__global__ __launch_bounds__(256) void k_fin_comb(const float* __restrict__ gesum, const float* __restrict__ pesum,
                                                  const float* __restrict__ countsf,
                                                  const float* __restrict__ temb, const int* __restrict__ tidx,
                                                  float* __restrict__ comb) {
    int b = blockIdx.x, t = threadIdx.x;
    float inv = 1.0f / countsf[b];
    float* o = comb + (size_t)b * 1280;
    o[t] = gesum[(size_t)b * 256 + t] * inv;
    o[768 + t] = temb[(size_t)tidx[b] * 256 + t];
    o[1024 + t] = pesum[(size_t)b * 256 + t] * inv;
}

// ---------------- two-layer MLP encoder: out = [relu](relu(vin@W1+b1)@W2+b2) ----------------
// One block per batch row; layer-1 output lives in LDS (no s1buf/t1buf round-trip; merges
// two k_dense launches into one). 4-way partial accumulators break the serial FMA chain.
__global__ __launch_bounds__(256) void k_enc2(const float* __restrict__ vin, int vs, int K1,
                                              const float* __restrict__ W1, const float* __restrict__ b1, int M1,
                                              const float* __restrict__ W2, const float* __restrict__ b2, int M2,
                                              float* __restrict__ out, int os, int oo) {
    __shared__ float vrow[1024];
    __shared__ float mid[256];
    const int b = blockIdx.x, tid = threadIdx.x;
    for (int k = tid; k < K1; k += 256) vrow[k] = vin[(size_t)b * vs + k];
    __syncthreads();
    if (tid < M1) {
        float a0 = 0.f, a1 = 0.f, a2 = 0.f, a3 = 0.f;
        int k = 0;
        for (; k + 3 < K1; k += 4) {
            a0 += vrow[k] * W1[(size_t)k * M1 + tid];
            a1 += vrow[k + 1] * W1[(size_t)(k + 1) * M1 + tid];
            a2 += vrow[k + 2] * W1[(size_t)(k + 2) * M1 + tid];
            a3 += vrow[k + 3] * W1[(size_t)(k + 3) * M1 + tid];
        }
        float acc = a0 + a1 + a2 + a3;
        for (; k < K1; ++k) acc += vrow[k] * W1[(size_t)k * M1 + tid];
        mid[tid] = fmaxf(acc + b1[tid], 0.f);
    }
    __syncthreads();
    if (tid < M2) {
        float a0 = 0.f, a1 = 0.f, a2 = 0.f, a3 = 0.f;
        for (int k = 0; k < M1; k += 4) {
            a0 += mid[k] * W2[(size_t)k * M2 + tid];
            a1 += mid[k + 1] * W2[(size_t)(k + 1) * M2 + tid];
            a2 += mid[k + 2] * W2[(size_t)(k + 2) * M2 + tid];
            a3 += mid[k + 3] * W2[(size_t)(k + 3) * M2 + tid];
        }
        out[(size_t)b * os + oo + tid] = a0 + a1 + a2 + a3 + b2[tid];
    }
}

// ---------------- head: parallel fp32 dense layer ----------------
__global__ __launch_bounds__(256) void k_dense(const float* __restrict__ vin, int vs,
                                               const float* __restrict__ W, const float* __restrict__ bias,
                                               float* __restrict__ out, int os, int oo,
                                               int K, int M, int relu) {
    const int b = blockIdx.y;
    const int wave = threadIdx.x >> 6, lane = threadIdx.x & 63;
    const int c = blockIdx.x * 64 + lane;
    const float* vrow = vin + (size_t)b * vs;
    float acc = 0.f;
    int k = wave;
    for (; k + 28 < K; k += 32) {
#pragma unroll
        for (int u = 0; u < 8; ++u)
            acc += vrow[k + 4 * u] * W[(size_t)(k + 4 * u) * M + c];
    }
    for (; k < K; k += 4)
        acc += vrow[k] * W[(size_t)k * M + c];
    __shared__ float red[4][64];
    red[wave][lane] = acc;
    __syncthreads();
    if (wave == 0) {
        float s = red[0][lane] + red[1][lane] + red[2][lane] + red[3][lane] + bias[c];
        if (relu) s = fmaxf(s, 0.f);
        out[(size_t)b * os + oo + c] = s;
    }
}

__global__ __launch_bounds__(256) void k_heads_small(const float* __restrict__ fused,
                                                     const float* __restrict__ Wg, const float* __restrict__ bg,
                                                     const float* __restrict__ Wtp, const float* __restrict__ btp,
                                                     float* __restrict__ out_logits, float* __restrict__ out_tp,
                                                     int NG) {
    __shared__ float lf[256];
    int b = blockIdx.x, tid = threadIdx.x;
    int wave = tid >> 6, lane = tid & 63;
    lf[tid] = fused[(size_t)b * 256 + tid];
    __syncthreads();
    for (int c = wave; c < NG; c += 4) {
        float s = 0.f;
#pragma unroll
        for (int k = lane; k < 256; k += 64) s += lf[k] * Wg[(size_t)k * NG + c];
#pragma unroll
        for (int off = 32; off > 0; off >>= 1) s += __shfl_down(s, off, 64);
        if (lane == 0) out_logits[(size_t)b * NG + c] = s + bg[c];
    }
    if (wave == 0) {
        float s = 0.f;
#pragma unroll
        for (int k = lane; k < 256; k += 64) s += lf[k] * Wtp[k];
#pragma unroll
        for (int off = 32; off > 0; off >>= 1) s += __shfl_down(s, off, 64);
        if (lane == 0) out_tp[b] = s + btp[0];
    }
}

// ---------------- host launch ----------------
extern "C" void kernel_launch(void* const* d_in, const int* in_sizes, int n_in,
                              void* d_out, int out_size, void* d_ws, size_t ws_size,
                              hipStream_t stream) {
    const float* x   = (const float*)d_in[0];
    const int* ei    = (const int*)d_in[1];
    const int* batch = (const int*)d_in[2];
    const float* sf  = (const float*)d_in[3];
    const float* tf  = (const float*)d_in[4];
    const int* tidx  = (const int*)d_in[5];
    const float* temb = (const float*)d_in[6];
    const float *Ws1 = (const float*)d_in[7],  *bs1 = (const float*)d_in[8];
    const float *Ws2 = (const float*)d_in[9],  *bs2 = (const float*)d_in[10];
    const float *Wc1 = (const float*)d_in[11], *bc1 = (const float*)d_in[12];
    const float *Wc2 = (const float*)d_in[13], *bc2 = (const float*)d_in[14];
    const float *Wc3 = (const float*)d_in[15], *bc3 = (const float*)d_in[16];
    const float *Wd1 = (const float*)d_in[17], *bd1 = (const float*)d_in[18];
    const float *Wd2 = (const float*)d_in[19], *bd2 = (const float*)d_in[20];
    const float *Wd3 = (const float*)d_in[21], *bd3 = (const float*)d_in[22];
    const float *Wt1 = (const float*)d_in[23], *bt1 = (const float*)d_in[24];
    const float *Wt2 = (const float*)d_in[25], *bt2 = (const float*)d_in[26];
    const float *Wp1 = (const float*)d_in[27], *bp1 = (const float*)d_in[28];
    const float *Wp2 = (const float*)d_in[29], *bp2 = (const float*)d_in[30];
    const float *Wf1 = (const float*)d_in[31], *bf1 = (const float*)d_in[32];
    const float *Wf2 = (const float*)d_in[33], *bf2 = (const float*)d_in[34];
    const float *Wg  = (const float*)d_in[35], *bg  = (const float*)d_in[36];
    const float *Wtp = (const float*)d_in[37], *btp = (const float*)d_in[38];

    const int N = in_sizes[2];
    const int E = in_sizes[1] / 2;
    const int B = in_sizes[5];
    const int DIN = in_sizes[0] / N;       // 128
    const int DS = in_sizes[3] / B;        // 1024
    const int NG = in_sizes[36];           // 20
    const int* src = ei;
    const int* dst = ei + E;

    // ---- workspace layout ----
    char* w = (char*)d_ws;
    ushort* A   = (ushort*)w;              w += (size_t)N * 256 * 2;
    ushort* Bb  = (ushort*)w;              w += (size_t)N * 256 * 2;
    ushort* xh  = (ushort*)w;              w += (size_t)N * 128 * 2;
    ushort* Wc1t = (ushort*)w;             w += 128 * 256 * 2;
    ushort* Wd1t = (ushort*)w;             w += 128 * 256 * 2;
    ushort* Wc2t = (ushort*)w;             w += 256 * 256 * 2;
    ushort* Wd2t = (ushort*)w;             w += 256 * 256 * 2;
    ushort* Wc3t = (ushort*)w;             w += 256 * 256 * 2;
    ushort* Wd3t = (ushort*)w;             w += 256 * 256 * 2;
    ushort* Wp1t = (ushort*)w;             w += 256 * 128 * 2;
    ushort* Wp2t = (ushort*)w;             w += 128 * 256 * 2;
    int* esrc   = (int*)w;                 w += (size_t)E * 4;
    float* ewt  = (float*)w;               w += (size_t)E * 4;
    int* cnt    = (int*)w;                 w += (size_t)N * 4;
    int* part   = (int*)w;                 w += (size_t)N * 4;
    int* rowptr = (int*)w;                 w += (size_t)(N + 1) * 4;
    int* fill   = (int*)w;                 w += (size_t)N * 4;
    int* bsums  = (int*)w;                 w += 1024 * 4;
    float* dinv = (float*)w;               w += (size_t)N * 4;
    float* selfw = (float*)w;              w += (size_t)N * 4;
    int* startp = (int*)w;                 w += (B + 1) * 4;
    float* countsf = (float*)w;            w += B * 4;
    float* ge = (float*)w;                 w += B * 256 * 4;   // ge then pe contiguous (zeroed together)
    float* pe = (float*)w;                 w += B * 256 * 4;
    float* s1buf = (float*)w;              w += B * 256 * 4;   // (unused after k_enc2 merge)
    float* t1buf = (float*)w;              w += B * 128 * 4;   // (unused after k_enc2 merge)
    float* comb = (float*)w;               w += B * 1280 * 4;
    float* fh = (float*)w;                 w += B * 512 * 4;

    float* out_fused = (float*)d_out;                 // B x 256
    float* out_logits = out_fused + (size_t)B * H;    // B x NG
    float* out_tp = out_logits + (size_t)B * NG;      // B x 1

    dim3 blk(256);
    const int nbN = (N + 255) / 256;
    const int nbE = (E + 255) / 256;

    // ---- CSR build ----
    k_zero2_i<<<dim3(nbN), blk, 0, stream>>>(cnt, fill, N);
    k_count_deg_i<<<dim3(nbE), blk, 0, stream>>>(dst, cnt, E);
    k_scan1<<<dim3(nbN), blk, 0, stream>>>(cnt, part, bsums, N);
    k_scan2<<<dim3(1), dim3(1024), 0, stream>>>(bsums, nbN);
    k_scan3<<<dim3(nbN), blk, 0, stream>>>(part, bsums, cnt, rowptr, dinv, selfw, N);
    k_scatter<<<dim3(nbE), blk, 0, stream>>>(src, dst, dinv, rowptr, fill, esrc, ewt, E);

    // ---- batched conversions + pooling prep ----
    {
        long nx = (long)N * DIN;
        long tot = nx + 2L * DIN * 256 + 4L * 65536 + 2L * 32768;
        k_prep<<<dim3((unsigned)((tot + 255) / 256)), blk, 0, stream>>>(
            x, xh, nx, DIN, Wc1, Wc1t, Wd1, Wd1t, Wc2, Wc2t, Wd2, Wd2t,
            Wc3, Wc3t, Wd3, Wd3t, Wp1, Wp1t, Wp2, Wp2t);
        k_ranges<<<dim3(1), dim3(128), 0, stream>>>(batch, N, B, startp, countsf);
        k_zero_f<<<dim3((2 * B * 256 + 255) / 256), blk, 0, stream>>>(ge, 2 * B * 256);
    }

    const int ngb4 = (N + 3) / 4;     // gather_b4: 4 nodes per 256-thread block (1/wave)
    const int ngb2 = (N + 15) / 16;   // gather_b2: 16 nodes per block (4/wave)
    const int nfb = (N + 63) / 64;

    // ---- static + temporal encoders (merged: one kernel per 2-layer MLP) ----
    k_enc2<<<dim3(B), blk, 0, stream>>>(sf, DS, DS, Ws1, bs1, 256, Ws2, bs2, 256, comb, 1280, 256);
    k_enc2<<<dim3(B), blk, 0, stream>>>(tf, 5, 5, Wt1, bt1, 128, Wt2, bt2, 256, comb, 1280, 512);

    // ---- 3 GCN layers (layer 3 fuses the ge mean-pool numerator) ----
    k_gather_b2<<<dim3(ngb2), blk, 0, stream>>>(xh, rowptr, esrc, ewt, selfw, A, N, 128, 128);
    k_fused_mfma<<<dim3(nfb), blk, 0, stream>>>(A, xh, Wc1t, Wd1t, bc1, bd1, Bb, N, 128, 128, 128, batch, ge, 0);
    k_gather_b4<<<dim3(ngb4), blk, 0, stream>>>(Bb, rowptr, esrc, ewt, selfw, A, N, 256, 256);
    k_fused_mfma<<<dim3(nfb), blk, 0, stream>>>(A, Bb, Wc2t, Wd2t, bc2, bd2, A, N, 256, 256, 256, batch, ge, 0);
    k_gather_b4<<<dim3(ngb4), blk, 0, stream>>>(A, rowptr, esrc, ewt, selfw, Bb, N, 256, 256);
    k_fused_mfma<<<dim3(nfb), blk, 0, stream>>>(Bb, A, Wc3t, Wd3t, bc3, bd3, Bb, N, 256, 256, 256, batch, ge, 1);

    // ---- fused pattern chain: p1 + p2 + pe-pool in one kernel ----
    k_pat_fused<<<dim3(nfb), blk, 0, stream>>>(Bb, Wp1t, Wp2t, bp1, bp2, batch, pe, N);
    k_fin_comb<<<dim3(B), blk, 0, stream>>>(ge, pe, countsf, temb, tidx, comb);

    // ---- head ----
    k_dense<<<dim3(8, B), blk, 0, stream>>>(comb, 1280, Wf1, bf1, fh, 512, 0, 1280, 512, 1);
    k_dense<<<dim3(4, B), blk, 0, stream>>>(fh, 512, Wf2, bf2, out_fused, 256, 0, 512, 256, 0);
    k_heads_small<<<dim3(B), blk, 0, stream>>>(out_fused, Wg, bg, Wtp, btp, out_logits, out_tp, NG);
}

// Round 9
// 794.581 us; speedup vs baseline: 1.0902x; 1.0858x over previous
//
#include <hip/hip_runtime.h>

#define H 256

typedef __attribute__((ext_vector_type(8))) short bf16x8;
typedef __attribute__((ext_vector_type(4))) float f32x4;

__device__ __forceinline__ float b2f(ushort h) {
    return __uint_as_float(((unsigned)h) << 16);
}
__device__ __forceinline__ float b2f_lo(unsigned u) {  // low bf16 of packed pair
    return __uint_as_float(u << 16);
}
__device__ __forceinline__ float b2f_hi(unsigned u) {  // high bf16 of packed pair
    return __uint_as_float(u & 0xffff0000u);
}
__device__ __forceinline__ ushort f2bf(float f) {
    unsigned u = __float_as_uint(f);
    unsigned r = (u + 0x7FFF + ((u >> 16) & 1)) >> 16;  // RNE
    return (ushort)r;
}
__device__ __forceinline__ unsigned pack2bf(float lo, float hi) {
    return (unsigned)f2bf(lo) | ((unsigned)f2bf(hi) << 16);
}

// async global->LDS DMA, 16B per lane, wave-uniform LDS base + lane*16 (HW-defined)
__device__ __forceinline__ void gload16(const ushort* g, const short* l) {
    __builtin_amdgcn_global_load_lds(
        (const __attribute__((address_space(1))) void*)(const void*)g,
        (__attribute__((address_space(3))) void*)(void*)l, 16, 0, 0);
}

// ---------------- CSR build ----------------
__global__ __launch_bounds__(256) void k_zero2_i(int* p, int* q, int n) {
    int i = blockIdx.x * 256 + threadIdx.x;
    if (i < n) { p[i] = 0; q[i] = 0; }
}

__global__ __launch_bounds__(256) void k_zero_f(float* p, int n) {
    int i = blockIdx.x * 256 + threadIdx.x;
    if (i < n) p[i] = 0.f;
}

__global__ __launch_bounds__(256) void k_count_deg_i(const int* __restrict__ dst, int* cnt, int E) {
    int i = blockIdx.x * 256 + threadIdx.x;
    if (i < E) atomicAdd(&cnt[dst[i]], 1);
}

__global__ __launch_bounds__(256) void k_scan1(const int* __restrict__ cnt, int* __restrict__ partial,
                                               int* __restrict__ bsums, int N) {
    __shared__ int s[256];
    int t = threadIdx.x;
    int idx = blockIdx.x * 256 + t;
    int v = idx < N ? cnt[idx] : 0;
    s[t] = v;
    __syncthreads();
    for (int off = 1; off < 256; off <<= 1) {
        int add = (t >= off) ? s[t - off] : 0;
        __syncthreads();
        s[t] += add;
        __syncthreads();
    }
    if (idx < N) partial[idx] = s[t];
    if (t == 255) bsums[blockIdx.x] = s[t];
}

__global__ __launch_bounds__(1024) void k_scan2(int* bsums, int nb) {
    __shared__ int s[1024];
    int t = threadIdx.x;
    s[t] = (t < nb) ? bsums[t] : 0;
    __syncthreads();
    for (int off = 1; off < 1024; off <<= 1) {
        int add = (t >= off) ? s[t - off] : 0;
        __syncthreads();
        s[t] += add;
        __syncthreads();
    }
    if (t < nb) bsums[t] = s[t];
}

// rowptr + dinv/selfw in one pass
__global__ __launch_bounds__(256) void k_scan3(const int* __restrict__ partial, const int* __restrict__ bsums,
                                               const int* __restrict__ cnt,
                                               int* __restrict__ rowptr, float* __restrict__ dinv,
                                               float* __restrict__ selfw, int N) {
    int idx = blockIdx.x * 256 + threadIdx.x;
    if (idx < N) {
        int off = blockIdx.x > 0 ? bsums[blockIdx.x - 1] : 0;
        rowptr[idx + 1] = partial[idx] + off;
        if (idx == 0) rowptr[0] = 0;
        float d = 1.0f + (float)cnt[idx];
        dinv[idx] = rsqrtf(d);
        selfw[idx] = 1.0f / d;
    }
}

__global__ __launch_bounds__(256) void k_scatter(const int* __restrict__ src, const int* __restrict__ dst,
                                                 const float* __restrict__ dinv, const int* __restrict__ rowptr,
                                                 int* __restrict__ fill, int* __restrict__ esrc,
                                                 float* __restrict__ ewt, int E) {
    int e = blockIdx.x * 256 + threadIdx.x;
    if (e >= E) return;
    int s = src[e], d = dst[e];
    int pos = rowptr[d] + atomicAdd(&fill[d], 1);
    esrc[pos] = s;
    ewt[pos] = dinv[s] * dinv[d];
}

// ---------------- batched conversions: x->bf16 + all 8 weight transposes ----------------
__device__ __forceinline__ void tcvt_one(long i, const float* __restrict__ W, ushort* __restrict__ Wt,
                                         int K, int M) {
    int k = (int)(i / M), m = (int)(i - (long)k * M);
    Wt[(size_t)m * K + k] = f2bf(W[(size_t)k * M + m]);
}

__global__ __launch_bounds__(256) void k_prep(
    const float* __restrict__ x, ushort* __restrict__ xh, long nx, int DIN,
    const float* __restrict__ Wc1, ushort* Wc1t, const float* __restrict__ Wd1, ushort* Wd1t,
    const float* __restrict__ Wc2, ushort* Wc2t, const float* __restrict__ Wd2, ushort* Wd2t,
    const float* __restrict__ Wc3, ushort* Wc3t, const float* __restrict__ Wd3, ushort* Wd3t,
    const float* __restrict__ Wp1, ushort* Wp1t, const float* __restrict__ Wp2, ushort* Wp2t) {
    long i = (long)blockIdx.x * 256 + threadIdx.x;
    if (i < nx) { xh[i] = f2bf(x[i]); return; }
    i -= nx;
    long n1 = (long)DIN * 256;
    if (i < n1) { tcvt_one(i, Wc1, Wc1t, DIN, 256); return; }
    i -= n1;
    if (i < n1) { tcvt_one(i, Wd1, Wd1t, DIN, 256); return; }
    i -= n1;
    if (i < 65536) { tcvt_one(i, Wc2, Wc2t, 256, 256); return; }
    i -= 65536;
    if (i < 65536) { tcvt_one(i, Wd2, Wd2t, 256, 256); return; }
    i -= 65536;
    if (i < 65536) { tcvt_one(i, Wc3, Wc3t, 256, 256); return; }
    i -= 65536;
    if (i < 65536) { tcvt_one(i, Wd3, Wd3t, 256, 256); return; }
    i -= 65536;
    if (i < 32768) { tcvt_one(i, Wp1, Wp1t, 256, 128); return; }
    i -= 32768;
    if (i < 32768) { tcvt_one(i, Wp2, Wp2t, 128, 256); return; }
}

// ---------------- CSR gather (bf16 in, fp32 acc, bf16 out) ----------------
// b4: 1 node per wave, ushort4/lane (proven fastest variant, round-2: 83.0us).
// Round-3 A/B showed the gather is service-rate-bound (random 512B granules), not
// latency/issue-bound: doubling bytes/instr and in-flight bytes changed nothing.
__global__ __launch_bounds__(256) void k_gather_b4(const ushort* __restrict__ xin, const int* __restrict__ rowptr,
                                                   const int* __restrict__ esrc, const float* __restrict__ ewt,
                                                   const float* __restrict__ selfw, ushort* __restrict__ p,
                                                   int N, int SX, int SP) {
    int node = blockIdx.x * 4 + (threadIdx.x >> 6);
    if (node >= N) return;
    int c = (threadIdx.x & 63) << 2;
    ushort4 h = *(const ushort4*)(xin + (size_t)node * SX + c);
    float sw = selfw[node];
    float a0 = b2f(h.x) * sw, a1 = b2f(h.y) * sw, a2 = b2f(h.z) * sw, a3 = b2f(h.w) * sw;
    int j = rowptr[node], r1 = rowptr[node + 1];
    for (; j + 3 < r1; j += 4) {
        int s0 = esrc[j], s1 = esrc[j + 1], s2 = esrc[j + 2], s3 = esrc[j + 3];
        float w0 = ewt[j], w1 = ewt[j + 1], w2 = ewt[j + 2], w3 = ewt[j + 3];
        ushort4 v0 = *(const ushort4*)(xin + (size_t)s0 * SX + c);
        ushort4 v1 = *(const ushort4*)(xin + (size_t)s1 * SX + c);
        ushort4 v2 = *(const ushort4*)(xin + (size_t)s2 * SX + c);
        ushort4 v3 = *(const ushort4*)(xin + (size_t)s3 * SX + c);
        a0 += b2f(v0.x) * w0 + b2f(v1.x) * w1 + b2f(v2.x) * w2 + b2f(v3.x) * w3;
        a1 += b2f(v0.y) * w0 + b2f(v1.y) * w1 + b2f(v2.y) * w2 + b2f(v3.y) * w3;
        a2 += b2f(v0.z) * w0 + b2f(v1.z) * w1 + b2f(v2.z) * w2 + b2f(v3.z) * w3;
        a3 += b2f(v0.w) * w0 + b2f(v1.w) * w1 + b2f(v2.w) * w2 + b2f(v3.w) * w3;
    }
    for (; j < r1; ++j) {
        int s0 = esrc[j];
        float w0 = ewt[j];
        ushort4 v0 = *(const ushort4*)(xin + (size_t)s0 * SX + c);
        a0 += b2f(v0.x) * w0; a1 += b2f(v0.y) * w0; a2 += b2f(v0.z) * w0; a3 += b2f(v0.w) * w0;
    }
    ushort4 o;
    o.x = f2bf(a0); o.y = f2bf(a1); o.z = f2bf(a2); o.w = f2bf(a3);
    *(ushort4*)(p + (size_t)node * SP + c) = o;
}

// 4 nodes per wave (16-lane group per node), 16B per lane covers a 256B (128-col) row.
__global__ __launch_bounds__(256) void k_gather_b2(const ushort* __restrict__ xin, const int* __restrict__ rowptr,
                                                   const int* __restrict__ esrc, const float* __restrict__ ewt,
                                                   const float* __restrict__ selfw, ushort* __restrict__ p,
                                                   int N, int SX, int SP) {
    int node = blockIdx.x * 16 + (threadIdx.x >> 4);
    bool act = node < N;
    int nn = act ? node : N - 1;
    int c = (threadIdx.x & 15) << 3;  // 8 cols (16B) per lane, 16 lanes = 128 cols
    uint4 hv = *(const uint4*)(xin + (size_t)nn * SX + c);
    float sw = selfw[nn];
    float a0 = b2f_lo(hv.x) * sw, a1 = b2f_hi(hv.x) * sw;
    float a2 = b2f_lo(hv.y) * sw, a3 = b2f_hi(hv.y) * sw;
    float a4 = b2f_lo(hv.z) * sw, a5 = b2f_hi(hv.z) * sw;
    float a6 = b2f_lo(hv.w) * sw, a7 = b2f_hi(hv.w) * sw;
    int j = act ? rowptr[nn] : 0, r1 = act ? rowptr[nn + 1] : 0;
    for (; j + 3 < r1; j += 4) {
        int s0 = esrc[j], s1 = esrc[j + 1], s2 = esrc[j + 2], s3 = esrc[j + 3];
        float w0 = ewt[j], w1 = ewt[j + 1], w2 = ewt[j + 2], w3 = ewt[j + 3];
        uint4 v0 = *(const uint4*)(xin + (size_t)s0 * SX + c);
        uint4 v1 = *(const uint4*)(xin + (size_t)s1 * SX + c);
        uint4 v2 = *(const uint4*)(xin + (size_t)s2 * SX + c);
        uint4 v3 = *(const uint4*)(xin + (size_t)s3 * SX + c);
        a0 += b2f_lo(v0.x) * w0 + b2f_lo(v1.x) * w1 + b2f_lo(v2.x) * w2 + b2f_lo(v3.x) * w3;
        a1 += b2f_hi(v0.x) * w0 + b2f_hi(v1.x) * w1 + b2f_hi(v2.x) * w2 + b2f_hi(v3.x) * w3;
        a2 += b2f_lo(v0.y) * w0 + b2f_lo(v1.y) * w1 + b2f_lo(v2.y) * w2 + b2f_lo(v3.y) * w3;
        a3 += b2f_hi(v0.y) * w0 + b2f_hi(v1.y) * w1 + b2f_hi(v2.y) * w2 + b2f_hi(v3.y) * w3;
        a4 += b2f_lo(v0.z) * w0 + b2f_lo(v1.z) * w1 + b2f_lo(v2.z) * w2 + b2f_lo(v3.z) * w3;
        a5 += b2f_hi(v0.z) * w0 + b2f_hi(v1.z) * w1 + b2f_hi(v2.z) * w2 + b2f_hi(v3.z) * w3;
        a6 += b2f_lo(v0.w) * w0 + b2f_lo(v1.w) * w1 + b2f_lo(v2.w) * w2 + b2f_lo(v3.w) * w3;
        a7 += b2f_hi(v0.w) * w0 + b2f_hi(v1.w) * w1 + b2f_hi(v2.w) * w2 + b2f_hi(v3.w) * w3;
    }
    for (; j < r1; ++j) {
        int s0 = esrc[j];
        float w0 = ewt[j];
        uint4 v0 = *(const uint4*)(xin + (size_t)s0 * SX + c);
        a0 += b2f_lo(v0.x) * w0; a1 += b2f_hi(v0.x) * w0;
        a2 += b2f_lo(v0.y) * w0; a3 += b2f_hi(v0.y) * w0;
        a4 += b2f_lo(v0.z) * w0; a5 += b2f_hi(v0.z) * w0;
        a6 += b2f_lo(v0.w) * w0; a7 += b2f_hi(v0.w) * w0;
    }
    if (act) {
        uint4 o;
        o.x = pack2bf(a0, a1); o.y = pack2bf(a2, a3);
        o.z = pack2bf(a4, a5); o.w = pack2bf(a6, a7);
        *(uint4*)(p + (size_t)node * SP + c) = o;
    }
}

// ---------------- fused dual-GEMM MFMA v3:  Out = relu(Pm@Wc + bc) + X@Wd + bd ----------------
// PROVEN best structure (round-6, 795.6us total). 64 rows x 256 cols per block, 4 waves,
// wave = 64-col slab, dual 4x4 acc, BK=64. global_load_lds width=16 staging, linear 128B LDS
// rows (8x16B slots), XOR-swizzle slot^(row&7) on BOTH pre-swizzled global source and ds_read
// (rule #21); measured SQ_LDS_BANK_CONFLICT == 0. LDS 80KB -> 2 blocks/CU.
// Round-7 lesson: do NOT move weights to per-lane global loads (83->114us: L2 latency lands
// inside every MFMA phase). Wave-shared LDS staging batches that latency into one drain/K-step.
// dopool: layer-3 epilogue accumulates the batch mean-pool numerator (ge); sbatch reuses Ps.
__global__ __launch_bounds__(256, 2) void k_fused_mfma(
    const ushort* __restrict__ Pm, const ushort* __restrict__ X,
    const ushort* __restrict__ Wct, const ushort* __restrict__ Wdt,
    const float* __restrict__ bc, const float* __restrict__ bd,
    ushort* __restrict__ Out, int N, int K, int SP, int SX,
    const int* __restrict__ batch, float* __restrict__ gesum, int dopool) {
    __shared__ __align__(16) short Ps[64 * 64];
    __shared__ __align__(16) short Xs[64 * 64];
    __shared__ __align__(16) short Wcs[256 * 64];
    __shared__ __align__(16) short Wds[256 * 64];
    const int tid = threadIdx.x;
    const int wave = tid >> 6, lane = tid & 63;
    const int row0 = blockIdx.x * 64;

    f32x4 accC[4][4], accD[4][4];
#pragma unroll
    for (int i = 0; i < 4; ++i)
#pragma unroll
        for (int j = 0; j < 4; ++j) { accC[i][j] = (f32x4)0.f; accD[i][j] = (f32x4)0.f; }

    const int lr = lane >> 3;          // staging: row within 8-row slab
    const int ls = lane & 7;           // staging: physical 16B slot within 128B row
    const int swz = (ls ^ lr) << 3;    // pre-swizzled source offset (halves)
    const int m = lane & 15, t4 = lane >> 4;

    for (int k0 = 0; k0 < K; k0 += 64) {
        // inputs: this wave stages rows [wave*16, wave*16+16) of Ps and Xs
#pragma unroll
        for (int i = 0; i < 2; ++i) {
            int rr = wave * 16 + i * 8;
            int gr = row0 + rr + lr; if (gr > N - 1) gr = N - 1;
            gload16(Pm + (size_t)gr * SP + k0 + swz, &Ps[rr * 64]);
            gload16(X + (size_t)gr * SX + k0 + swz, &Xs[rr * 64]);
        }
        // weights: this wave stages its own col block [wave*64, wave*64+64)
#pragma unroll
        for (int i = 0; i < 8; ++i) {
            int cc = wave * 64 + i * 8;
            gload16(Wct + (size_t)(cc + lr) * K + k0 + swz, &Wcs[cc * 64]);
            gload16(Wdt + (size_t)(cc + lr) * K + k0 + swz, &Wds[cc * 64]);
        }
        __syncthreads();  // drains vmcnt(0): all DMA landed

#pragma unroll
        for (int h = 0; h < 2; ++h) {
            const int slot = h * 4 + t4;
            bf16x8 aP[4], aX[4], bC[4], bD[4];
#pragma unroll
            for (int i = 0; i < 4; ++i) {
                int r = 16 * i + m;
                int off = r * 64 + ((slot ^ (r & 7)) << 3);
                aP[i] = *(bf16x8*)&Ps[off];
                aX[i] = *(bf16x8*)&Xs[off];
            }
#pragma unroll
            for (int j = 0; j < 4; ++j) {
                int c = wave * 64 + 16 * j + m;
                int off = c * 64 + ((slot ^ (c & 7)) << 3);
                bC[j] = *(bf16x8*)&Wcs[off];
                bD[j] = *(bf16x8*)&Wds[off];
            }
#pragma unroll
            for (int i = 0; i < 4; ++i)
#pragma unroll
                for (int j = 0; j < 4; ++j) {
                    accC[i][j] = __builtin_amdgcn_mfma_f32_16x16x32_bf16(aP[i], bC[j], accC[i][j], 0, 0, 0);
                    accD[i][j] = __builtin_amdgcn_mfma_f32_16x16x32_bf16(aX[i], bD[j], accD[i][j], 0, 0, 0);
                }
        }
        __syncthreads();  // protect LDS before next K-step's DMA
    }

    // after the last trailing barrier every wave is done with LDS -> Ps region reusable
    int* sb = (int*)Ps;
    if (dopool && tid < 64) {
        int r = row0 + tid;
        sb[tid] = batch[r < N ? r : (N - 1)];
    }

    const int rq = t4 * 4;
#pragma unroll
    for (int j = 0; j < 4; ++j) {
        int col = wave * 64 + 16 * j + m;
        float bcv = bc[col], bdv = bd[col];
#pragma unroll
        for (int i = 0; i < 4; ++i)
#pragma unroll
            for (int g = 0; g < 4; ++g) {
                int row = row0 + 16 * i + rq + g;
                if (row < N) {
                    float v = fmaxf(accC[i][j][g] + bcv, 0.f) + accD[i][j][g] + bdv;
                    Out[(size_t)row * 256 + col] = f2bf(v);
                }
            }
    }

    if (dopool) {
        __syncthreads();
        const int g0 = sb[0], g1 = sb[63];
        for (int g = g0; g <= g1; ++g) {
#pragma unroll
            for (int j = 0; j < 4; ++j) {
                int col = wave * 64 + 16 * j + m;
                float bcv = bc[col], bdv = bd[col];
                float s = 0.f;
#pragma unroll
                for (int i = 0; i < 4; ++i)
#pragma unroll
                    for (int q = 0; q < 4; ++q) {
                        int rl = 16 * i + rq + q;
                        bool ok = (sb[rl] == g) && (row0 + rl < N);
                        float v = fmaxf(accC[i][j][q] + bcv, 0.f) + accD[i][j][q] + bdv;
                        s += ok ? v : 0.f;
                    }
                s += __shfl_down(s, 32, 64);
                s += __shfl_down(s, 16, 64);
                if (lane < 16) atomicAdd(&gesum[(size_t)g * 256 + wave * 64 + 16 * j + lane], s);
            }
        }
    }
}

// ---------------- fused pattern chain v2: pe += pool(relu(relu(Bb@Wp1+bp1)@Wp2+bp2)) ----------
// GEMM2 runs in two 128-col halves through ONE 32KB Wp2 staging buffer. Half-0's staging is
// issued at kernel entry (drained for free by GEMM1's first barrier); only half-1's 32KB stage is
// exposed, overlapped by the co-resident block. LDS = 32+16+8+16KB + sbatch ~= 72.3KB -> 2 blocks/CU.
__global__ __launch_bounds__(256, 2) void k_pat_fused(
    const ushort* __restrict__ Bb, const ushort* __restrict__ Wp1t, const ushort* __restrict__ Wp2t,
    const float* __restrict__ bp1, const float* __restrict__ bp2,
    const int* __restrict__ batch, float* __restrict__ pesum, int N) {
    __shared__ __align__(16) short Wp2s[128 * 128];  // 32KB: one 128-col half of Wp2 at a time
    __shared__ __align__(16) short Wp1s[128 * 64];   // 16KB
    __shared__ __align__(16) short Bbs[64 * 64];     // 8KB
    __shared__ __align__(16) short Ts[64 * 128];     // 16KB
    __shared__ int sbatch[64];
    const int tid = threadIdx.x;
    const int wave = tid >> 6, lane = tid & 63;
    const int row0 = blockIdx.x * 64;
    const int m = lane & 15, t4 = lane >> 4;
    const int lr = lane >> 3, ls = lane & 7;
    const int swz = (ls ^ lr) << 3;
    const int rl4 = lane >> 4;   // Wp2 staging: row within 4-row slab
    const int sl = lane & 15;    // Wp2 staging: physical 16B slot within 256B row

    if (tid < 64) {
        int r = row0 + tid;
        sbatch[tid] = batch[r < N ? r : (N - 1)];
    }

    // issue Wp2 half-0 staging EARLY; it drains under GEMM1's first barrier.
    // wave w stages local cols [w*32, w*32+32): 8 instrs of 4 rows (1KB) each.
#pragma unroll
    for (int it = 0; it < 8; ++it) {
        int c0 = wave * 32 + it * 4;
        int c = c0 + rl4;
        gload16(Wp2t + (size_t)c * 128 + ((sl ^ (c & 15)) << 3), &Wp2s[c0 * 128]);
    }

    // ---- GEMM1: t = relu(Bb@Wp1 + bp1), 64x128, K=256, wave = 32-col slab ----
    f32x4 acc1[4][2];
#pragma unroll
    for (int i = 0; i < 4; ++i)
#pragma unroll
        for (int j = 0; j < 2; ++j) acc1[i][j] = (f32x4)0.f;

    for (int k0 = 0; k0 < 256; k0 += 64) {
#pragma unroll
        for (int i = 0; i < 2; ++i) {
            int rr = wave * 16 + i * 8;
            int gr = row0 + rr + lr; if (gr > N - 1) gr = N - 1;
            gload16(Bb + (size_t)gr * 256 + k0 + swz, &Bbs[rr * 64]);
        }
#pragma unroll
        for (int i = 0; i < 4; ++i) {
            int cc = wave * 32 + i * 8;
            gload16(Wp1t + (size_t)(cc + lr) * 256 + k0 + swz, &Wp1s[cc * 64]);
        }
        __syncthreads();  // drains vmcnt(0) (incl. Wp2 half-0 preload on first pass)
#pragma unroll
        for (int h = 0; h < 2; ++h) {
            const int slot = h * 4 + t4;
            bf16x8 aB[4], bW[2];
#pragma unroll
            for (int i = 0; i < 4; ++i) {
                int r = 16 * i + m;
                aB[i] = *(bf16x8*)&Bbs[r * 64 + ((slot ^ (r & 7)) << 3)];
            }
#pragma unroll
            for (int j = 0; j < 2; ++j) {
                int c = wave * 32 + 16 * j + m;
                bW[j] = *(bf16x8*)&Wp1s[c * 64 + ((slot ^ (c & 7)) << 3)];
            }
#pragma unroll
            for (int i = 0; i < 4; ++i)
#pragma unroll
                for (int j = 0; j < 2; ++j)
                    acc1[i][j] = __builtin_amdgcn_mfma_f32_16x16x32_bf16(aB[i], bW[j], acc1[i][j], 0, 0, 0);
        }
        __syncthreads();
    }

    // GEMM1 epilogue -> Ts (bf16, relu+bias), swizzled 16-slot rows
    const int rq = t4 * 4;
#pragma unroll
    for (int j = 0; j < 2; ++j) {
        int col = wave * 32 + 16 * j + m;
        float bv = bp1[col];
#pragma unroll
        for (int i = 0; i < 4; ++i)
#pragma unroll
            for (int g = 0; g < 4; ++g) {
                int r = 16 * i + rq + g;
                float v = fmaxf(acc1[i][j][g] + bv, 0.f);
                Ts[r * 128 + (((col >> 3) ^ (r & 15)) << 3) + (col & 7)] = (short)f2bf(v);
            }
    }
    __syncthreads();

    // ---- GEMM2 + pool, two 128-col halves:  pat = relu(t@Wp2 + bp2) ----
    const int g0 = sbatch[0];
    const int g1 = sbatch[63];
    for (int hh = 0; hh < 2; ++hh) {
        if (hh == 1) {
            __syncthreads();  // all waves done reading Wp2s half-0
#pragma unroll
            for (int it = 0; it < 8; ++it) {
                int c0 = wave * 32 + it * 4;
                int c = c0 + rl4;
                gload16(Wp2t + (size_t)(128 + c) * 128 + ((sl ^ (c & 15)) << 3), &Wp2s[c0 * 128]);
            }
            __syncthreads();  // drain half-1 DMA
        }

        f32x4 acc2[4][2];
#pragma unroll
        for (int i = 0; i < 4; ++i)
#pragma unroll
            for (int j = 0; j < 2; ++j) acc2[i][j] = (f32x4)0.f;

#pragma unroll
        for (int sl4 = 0; sl4 < 4; ++sl4) {
            const int s16 = sl4 * 4 + t4;
            bf16x8 af[4], bf[2];
#pragma unroll
            for (int i = 0; i < 4; ++i) {
                int r = 16 * i + m;
                af[i] = *(bf16x8*)&Ts[r * 128 + ((s16 ^ (r & 15)) << 3)];
            }
#pragma unroll
            for (int j = 0; j < 2; ++j) {
                int cl = wave * 32 + 16 * j + m;
                bf[j] = *(bf16x8*)&Wp2s[cl * 128 + ((s16 ^ (cl & 15)) << 3)];
            }
#pragma unroll
            for (int i = 0; i < 4; ++i)
#pragma unroll
                for (int j = 0; j < 2; ++j)
                    acc2[i][j] = __builtin_amdgcn_mfma_f32_16x16x32_bf16(af[i], bf[j], acc2[i][j], 0, 0, 0);
        }

        // pooled epilogue for this half's columns
        for (int g = g0; g <= g1; ++g) {
#pragma unroll
            for (int j = 0; j < 2; ++j) {
                int col = hh * 128 + wave * 32 + 16 * j + m;
                float bv = bp2[col];
                float s = 0.f;
#pragma unroll
                for (int i = 0; i < 4; ++i)
#pragma unroll
                    for (int q = 0; q < 4; ++q) {
                        int rl = 16 * i + rq + q;
                        bool ok = (sbatch[rl] == g) && (row0 + rl < N);
                        float v = fmaxf(acc2[i][j][q] + bv, 0.f);
                        s += ok ? v : 0.f;
                    }
                s += __shfl_down(s, 32, 64);
                s += __shfl_down(s, 16, 64);
                if (lane < 16) atomicAdd(&pesum[(size_t)g * 256 + hh * 128 + wave * 32 + 16 * j + lane], s);
            }
        }
    }
}

// ---------------- pooling helpers ----------------
__global__ void k_ranges(const int* __restrict__ batch, int N, int B, int* __restrict__ start,
                         float* __restrict__ countsf) {
    int b = threadIdx.x;
    if (b <= B) {
        int lo = 0, hi = N;
        while (lo < hi) {
            int mid = (lo + hi) >> 1;
            if (batch[mid] < b) lo = mid + 1; else hi = mid;
        }
        start[b] = lo;
    }
    __syncthreads();
    if (b < B) {
        int cnt = start[b + 1] - start[b];
        countsf[b] = (float)(cnt > 0 ? cnt : 1);
    }
}

// finalize pools + assemble comb in one pass
__global__ __launch_bounds__(256) void k_fin_comb(const float* __restrict__ gesum, const float* __restrict__ pesum,
                                                  const float* __restrict__ countsf,
                                                  const float* __restrict__ temb, const int* __restrict__ tidx,
                                                  float* __restrict__ comb) {
    int b = blockIdx.x, t = threadIdx.x;
    float inv = 1.0f / countsf[b];
    float* o = comb + (size_t)b * 1280;
    o[t] = gesum[(size_t)b * 256 + t] * inv;
    o[768 + t] = temb[(size_t)tidx[b] * 256 + t];
    o[1024 + t] = pesum[(size_t)b * 256 + t] * inv;
}

// ---------------- head: parallel fp32 dense layer ----------------
// (Round-8 lesson: do NOT merge 2-layer MLPs into one block-per-row kernel — grid collapse
// 256->64 blocks put the static encoder at 2.8% occupancy, 83us. Keep K split across waves.)
__global__ __launch_bounds__(256) void k_dense(const float* __restrict__ vin, int vs,
                                               const float* __restrict__ W, const float* __restrict__ bias,
                                               float* __restrict__ out, int os, int oo,
                                               int K, int M, int relu) {
    const int b = blockIdx.y;
    const int wave = threadIdx.x >> 6, lane = threadIdx.x & 63;
    const int c = blockIdx.x * 64 + lane;
    const float* vrow = vin + (size_t)b * vs;
    float acc = 0.f;
    int k = wave;
    for (; k + 28 < K; k += 32) {
#pragma unroll
        for (int u = 0; u < 8; ++u)
            acc += vrow[k + 4 * u] * W[(size_t)(k + 4 * u) * M + c];
    }
    for (; k < K; k += 4)
        acc += vrow[k] * W[(size_t)k * M + c];
    __shared__ float red[4][64];
    red[wave][lane] = acc;
    __syncthreads();
    if (wave == 0) {
        float s = red[0][lane] + red[1][lane] + red[2][lane] + red[3][lane] + bias[c];
        if (relu) s = fmaxf(s, 0.f);
        out[(size_t)b * os + oo + c] = s;
    }
}

__global__ __launch_bounds__(256) void k_heads_small(const float* __restrict__ fused,
                                                     const float* __restrict__ Wg, const float* __restrict__ bg,
                                                     const float* __restrict__ Wtp, const float* __restrict__ btp,
                                                     float* __restrict__ out_logits, float* __restrict__ out_tp,
                                                     int NG) {
    __shared__ float lf[256];
    int b = blockIdx.x, tid = threadIdx.x;
    int wave = tid >> 6, lane = tid & 63;
    lf[tid] = fused[(size_t)b * 256 + tid];
    __syncthreads();
    for (int c = wave; c < NG; c += 4) {
        float s = 0.f;
#pragma unroll
        for (int k = lane; k < 256; k += 64) s += lf[k] * Wg[(size_t)k * NG + c];
#pragma unroll
        for (int off = 32; off > 0; off >>= 1) s += __shfl_down(s, off, 64);
        if (lane == 0) out_logits[(size_t)b * NG + c] = s + bg[c];
    }
    if (wave == 0) {
        float s = 0.f;
#pragma unroll
        for (int k = lane; k < 256; k += 64) s += lf[k] * Wtp[k];
#pragma unroll
        for (int off = 32; off > 0; off >>= 1) s += __shfl_down(s, off, 64);
        if (lane == 0) out_tp[b] = s + btp[0];
    }
}

// ---------------- host launch ----------------
extern "C" void kernel_launch(void* const* d_in, const int* in_sizes, int n_in,
                              void* d_out, int out_size, void* d_ws, size_t ws_size,
                              hipStream_t stream) {
    const float* x   = (const float*)d_in[0];
    const int* ei    = (const int*)d_in[1];
    const int* batch = (const int*)d_in[2];
    const float* sf  = (const float*)d_in[3];
    const float* tf  = (const float*)d_in[4];
    const int* tidx  = (const int*)d_in[5];
    const float* temb = (const float*)d_in[6];
    const float *Ws1 = (const float*)d_in[7],  *bs1 = (const float*)d_in[8];
    const float *Ws2 = (const float*)d_in[9],  *bs2 = (const float*)d_in[10];
    const float *Wc1 = (const float*)d_in[11], *bc1 = (const float*)d_in[12];
    const float *Wc2 = (const float*)d_in[13], *bc2 = (const float*)d_in[14];
    const float *Wc3 = (const float*)d_in[15], *bc3 = (const float*)d_in[16];
    const float *Wd1 = (const float*)d_in[17], *bd1 = (const float*)d_in[18];
    const float *Wd2 = (const float*)d_in[19], *bd2 = (const float*)d_in[20];
    const float *Wd3 = (const float*)d_in[21], *bd3 = (const float*)d_in[22];
    const float *Wt1 = (const float*)d_in[23], *bt1 = (const float*)d_in[24];
    const float *Wt2 = (const float*)d_in[25], *bt2 = (const float*)d_in[26];
    const float *Wp1 = (const float*)d_in[27], *bp1 = (const float*)d_in[28];
    const float *Wp2 = (const float*)d_in[29], *bp2 = (const float*)d_in[30];
    const float *Wf1 = (const float*)d_in[31], *bf1 = (const float*)d_in[32];
    const float *Wf2 = (const float*)d_in[33], *bf2 = (const float*)d_in[34];
    const float *Wg  = (const float*)d_in[35], *bg  = (const float*)d_in[36];
    const float *Wtp = (const float*)d_in[37], *btp = (const float*)d_in[38];

    const int N = in_sizes[2];
    const int E = in_sizes[1] / 2;
    const int B = in_sizes[5];
    const int DIN = in_sizes[0] / N;       // 128
    const int DS = in_sizes[3] / B;        // 1024
    const int NG = in_sizes[36];           // 20
    const int* src = ei;
    const int* dst = ei + E;

    // ---- workspace layout ----
    char* w = (char*)d_ws;
    ushort* A   = (ushort*)w;              w += (size_t)N * 256 * 2;
    ushort* Bb  = (ushort*)w;              w += (size_t)N * 256 * 2;
    ushort* xh  = (ushort*)w;              w += (size_t)N * 128 * 2;
    ushort* Wc1t = (ushort*)w;             w += 128 * 256 * 2;
    ushort* Wd1t = (ushort*)w;             w += 128 * 256 * 2;
    ushort* Wc2t = (ushort*)w;             w += 256 * 256 * 2;
    ushort* Wd2t = (ushort*)w;             w += 256 * 256 * 2;
    ushort* Wc3t = (ushort*)w;             w += 256 * 256 * 2;
    ushort* Wd3t = (ushort*)w;             w += 256 * 256 * 2;
    ushort* Wp1t = (ushort*)w;             w += 256 * 128 * 2;
    ushort* Wp2t = (ushort*)w;             w += 128 * 256 * 2;
    int* esrc   = (int*)w;                 w += (size_t)E * 4;
    float* ewt  = (float*)w;               w += (size_t)E * 4;
    int* cnt    = (int*)w;                 w += (size_t)N * 4;
    int* part   = (int*)w;                 w += (size_t)N * 4;
    int* rowptr = (int*)w;                 w += (size_t)(N + 1) * 4;
    int* fill   = (int*)w;                 w += (size_t)N * 4;
    int* bsums  = (int*)w;                 w += 1024 * 4;
    float* dinv = (float*)w;               w += (size_t)N * 4;
    float* selfw = (float*)w;              w += (size_t)N * 4;
    int* startp = (int*)w;                 w += (B + 1) * 4;
    float* countsf = (float*)w;            w += B * 4;
    float* ge = (float*)w;                 w += B * 256 * 4;   // ge then pe contiguous (zeroed together)
    float* pe = (float*)w;                 w += B * 256 * 4;
    float* s1buf = (float*)w;              w += B * 256 * 4;
    float* t1buf = (float*)w;              w += B * 128 * 4;
    float* comb = (float*)w;               w += B * 1280 * 4;
    float* fh = (float*)w;                 w += B * 512 * 4;

    float* out_fused = (float*)d_out;                 // B x 256
    float* out_logits = out_fused + (size_t)B * H;    // B x NG
    float* out_tp = out_logits + (size_t)B * NG;      // B x 1

    dim3 blk(256);
    const int nbN = (N + 255) / 256;
    const int nbE = (E + 255) / 256;

    // ---- CSR build ----
    k_zero2_i<<<dim3(nbN), blk, 0, stream>>>(cnt, fill, N);
    k_count_deg_i<<<dim3(nbE), blk, 0, stream>>>(dst, cnt, E);
    k_scan1<<<dim3(nbN), blk, 0, stream>>>(cnt, part, bsums, N);
    k_scan2<<<dim3(1), dim3(1024), 0, stream>>>(bsums, nbN);
    k_scan3<<<dim3(nbN), blk, 0, stream>>>(part, bsums, cnt, rowptr, dinv, selfw, N);
    k_scatter<<<dim3(nbE), blk, 0, stream>>>(src, dst, dinv, rowptr, fill, esrc, ewt, E);

    // ---- batched conversions + pooling prep ----
    {
        long nx = (long)N * DIN;
        long tot = nx + 2L * DIN * 256 + 4L * 65536 + 2L * 32768;
        k_prep<<<dim3((unsigned)((tot + 255) / 256)), blk, 0, stream>>>(
            x, xh, nx, DIN, Wc1, Wc1t, Wd1, Wd1t, Wc2, Wc2t, Wd2, Wd2t,
            Wc3, Wc3t, Wd3, Wd3t, Wp1, Wp1t, Wp2, Wp2t);
        k_ranges<<<dim3(1), dim3(128), 0, stream>>>(batch, N, B, startp, countsf);
        k_zero_f<<<dim3((2 * B * 256 + 255) / 256), blk, 0, stream>>>(ge, 2 * B * 256);
    }

    const int ngb4 = (N + 3) / 4;     // gather_b4: 4 nodes per 256-thread block (1/wave)
    const int ngb2 = (N + 15) / 16;   // gather_b2: 16 nodes per block (4/wave)
    const int nfb = (N + 63) / 64;

    // ---- static + temporal encoders ----
    k_dense<<<dim3(4, B), blk, 0, stream>>>(sf, DS, Ws1, bs1, s1buf, 256, 0, DS, 256, 1);
    k_dense<<<dim3(4, B), blk, 0, stream>>>(s1buf, 256, Ws2, bs2, comb, 1280, 256, 256, 256, 0);
    k_dense<<<dim3(2, B), blk, 0, stream>>>(tf, 5, Wt1, bt1, t1buf, 128, 0, 5, 128, 1);
    k_dense<<<dim3(4, B), blk, 0, stream>>>(t1buf, 128, Wt2, bt2, comb, 1280, 512, 128, 256, 0);

    // ---- 3 GCN layers (layer 3 fuses the ge mean-pool numerator) ----
    k_gather_b2<<<dim3(ngb2), blk, 0, stream>>>(xh, rowptr, esrc, ewt, selfw, A, N, 128, 128);
    k_fused_mfma<<<dim3(nfb), blk, 0, stream>>>(A, xh, Wc1t, Wd1t, bc1, bd1, Bb, N, 128, 128, 128, batch, ge, 0);
    k_gather_b4<<<dim3(ngb4), blk, 0, stream>>>(Bb, rowptr, esrc, ewt, selfw, A, N, 256, 256);
    k_fused_mfma<<<dim3(nfb), blk, 0, stream>>>(A, Bb, Wc2t, Wd2t, bc2, bd2, A, N, 256, 256, 256, batch, ge, 0);
    k_gather_b4<<<dim3(ngb4), blk, 0, stream>>>(A, rowptr, esrc, ewt, selfw, Bb, N, 256, 256);
    k_fused_mfma<<<dim3(nfb), blk, 0, stream>>>(Bb, A, Wc3t, Wd3t, bc3, bd3, Bb, N, 256, 256, 256, batch, ge, 1);

    // ---- fused pattern chain: p1 + p2 + pe-pool in one kernel ----
    k_pat_fused<<<dim3(nfb), blk, 0, stream>>>(Bb, Wp1t, Wp2t, bp1, bp2, batch, pe, N);
    k_fin_comb<<<dim3(B), blk, 0, stream>>>(ge, pe, countsf, temb, tidx, comb);

    // ---- head ----
    k_dense<<<dim3(8, B), blk, 0, stream>>>(comb, 1280, Wf1, bf1, fh, 512, 0, 1280, 512, 1);
    k_dense<<<dim3(4, B), blk, 0, stream>>>(fh, 512, Wf2, bf2, out_fused, 256, 0, 512, 256, 0);
    k_heads_small<<<dim3(B), blk, 0, stream>>>(out_fused, Wg, bg, Wtp, btp, out_logits, out_tp, NG);
}